// Round 1
// baseline (569.247 us; speedup 1.0000x reference)
//
#include <hip/hip_runtime.h>
#include <hip/hip_bf16.h>
#include <math.h>

#define N_NODES 50000
#define N_EDGES 600000
#define N_GRAPHS 512
#define LN_EPS 1e-5f

// ---------------------------------------------------------------------------
// h0 = concat([x (29), xdims (3), st_emb[xsttype] (12)]) -> [N, 44]
__global__ void h0_kernel(const float* __restrict__ x,
                          const float* __restrict__ xdims,
                          const int* __restrict__ stt,
                          const float* __restrict__ st_emb,
                          float* __restrict__ h0)
{
    int idx = blockIdx.x * blockDim.x + threadIdx.x;
    if (idx >= N_NODES * 44) return;
    int n = idx / 44;
    int c = idx - n * 44;
    float v;
    if (c < 29)       v = x[n * 29 + c];
    else if (c < 32)  v = xdims[n * 3 + (c - 29)];
    else              v = st_emb[stt[n] * 12 + (c - 32)];
    h0[idx] = v;
}

// ---------------------------------------------------------------------------
// degree histogram over dst
__global__ void count_kernel(const int* __restrict__ dst, int* __restrict__ cnt)
{
    int e = blockIdx.x * blockDim.x + threadIdx.x;
    if (e < N_EDGES) atomicAdd(&cnt[dst[e]], 1);
}

// single-block exclusive scan (Hillis-Steele over 1024-chunks with carry)
__global__ void scan_kernel(const int* __restrict__ cnt, int* __restrict__ offs, int n)
{
    __shared__ int s[1024];
    __shared__ int carry_sh;
    if (threadIdx.x == 0) carry_sh = 0;
    __syncthreads();
    for (int base = 0; base < n; base += 1024) {
        int i = base + (int)threadIdx.x;
        int v = (i < n) ? cnt[i] : 0;
        s[threadIdx.x] = v;
        __syncthreads();
        #pragma unroll
        for (int d = 1; d < 1024; d <<= 1) {
            int t = (threadIdx.x >= (unsigned)d) ? s[threadIdx.x - d] : 0;
            __syncthreads();
            s[threadIdx.x] += t;
            __syncthreads();
        }
        int incl = s[threadIdx.x];
        int carry = carry_sh;
        if (i < n) offs[i] = carry + incl - v;   // exclusive
        __syncthreads();
        if (threadIdx.x == 1023) carry_sh = carry + s[1023];
        __syncthreads();
    }
    if (threadIdx.x == 0) offs[n] = carry_sh;
}

__global__ void copy_int_kernel(const int* __restrict__ src, int* __restrict__ dstp, int n)
{
    int i = blockIdx.x * blockDim.x + threadIdx.x;
    if (i < n) dstp[i] = src[i];
}

// scatter edges into CSR slots
__global__ void fill_kernel(const int* __restrict__ esrc_in, const int* __restrict__ edst_in,
                            int* __restrict__ pos, int* __restrict__ esrc_out)
{
    int e = blockIdx.x * blockDim.x + threadIdx.x;
    if (e < N_EDGES) {
        int p = atomicAdd(&pos[edst_in[e]], 1);
        esrc_out[p] = esrc_in[e];
    }
}

// ---------------------------------------------------------------------------
// per-node neighbor mean via CSR gather (one block per node; writes, no atomics)
template <int D>
__global__ void agg_kernel(const float* __restrict__ h,
                           const int* __restrict__ offs,
                           const int* __restrict__ esrc,
                           float* __restrict__ meanout)
{
    int n = blockIdx.x;
    int d = threadIdx.x;
    int s0 = offs[n], s1 = offs[n + 1];
    float acc = 0.f;
    for (int e = s0; e < s1; ++e) {
        int src = esrc[e];
        if (d < D) acc += h[(size_t)src * D + d];
    }
    float inv = (s1 > s0) ? (1.0f / (float)(s1 - s0)) : 0.0f;
    if (d < D) meanout[(size_t)n * D + d] = acc * inv;
}

// ---------------------------------------------------------------------------
// fused: out = LN(mean @ Wl^T + bl + h @ Wr^T) * g + beta, relu -> hout [N,128]
// tile: 32 nodes x 128 feats per block (256 thr); thread = 4 nodes x 4 feats
template <int DIN>
__global__ __launch_bounds__(256) void layer_kernel(
    const float* __restrict__ hin, const float* __restrict__ meanin,
    const float* __restrict__ Wl, const float* __restrict__ bl,
    const float* __restrict__ Wr, const float* __restrict__ gvec,
    const float* __restrict__ beta, float* __restrict__ hout)
{
    constexpr int TN = 32;
    __shared__ float xs[TN][2 * DIN];   // [node][mean(0..DIN-1) | h(DIN..2DIN-1)]
    const int tid = threadIdx.x;
    const int n0 = blockIdx.x * TN;

    for (int i = tid; i < TN * DIN; i += 256) {
        int n = i / DIN, k = i - n * DIN;
        int gn = n0 + n; if (gn >= N_NODES) gn = N_NODES - 1;
        xs[n][k]       = meanin[(size_t)gn * DIN + k];
        xs[n][DIN + k] = hin[(size_t)gn * DIN + k];
    }
    __syncthreads();

    const int f4 = tid & 31;   // feats f4*4 .. f4*4+3
    const int ng = tid >> 5;   // nodes ng*4 .. ng*4+3

    float b0[4], gg[4], bb[4];
    #pragma unroll
    for (int f = 0; f < 4; ++f) {
        b0[f] = bl[f4 * 4 + f];
        gg[f] = gvec[f4 * 4 + f];
        bb[f] = beta[f4 * 4 + f];
    }

    float acc[4][4];
    #pragma unroll
    for (int i = 0; i < 4; ++i)
        #pragma unroll
        for (int f = 0; f < 4; ++f) acc[i][f] = b0[f];

    const float* wlp = Wl + (size_t)(f4 * 4) * DIN;
    const float* wrp = Wr + (size_t)(f4 * 4) * DIN;

    for (int k = 0; k < DIN; k += 4) {
        float4 wl[4], wr[4];
        #pragma unroll
        for (int f = 0; f < 4; ++f) {
            wl[f] = *(const float4*)(wlp + (size_t)f * DIN + k);
            wr[f] = *(const float4*)(wrp + (size_t)f * DIN + k);
        }
        #pragma unroll
        for (int i = 0; i < 4; ++i) {
            int n = ng * 4 + i;
            float4 xm = *(const float4*)(&xs[n][k]);
            float4 xh = *(const float4*)(&xs[n][DIN + k]);
            #pragma unroll
            for (int f = 0; f < 4; ++f) {
                acc[i][f] += xm.x * wl[f].x + xm.y * wl[f].y + xm.z * wl[f].z + xm.w * wl[f].w
                           + xh.x * wr[f].x + xh.y * wr[f].y + xh.z * wr[f].z + xh.w * wr[f].w;
            }
        }
    }

    // LayerNorm per node: 128 feats live in the 32 lanes sharing this ng
    #pragma unroll
    for (int i = 0; i < 4; ++i) {
        float s1 = acc[i][0] + acc[i][1] + acc[i][2] + acc[i][3];
        float s2 = acc[i][0] * acc[i][0] + acc[i][1] * acc[i][1]
                 + acc[i][2] * acc[i][2] + acc[i][3] * acc[i][3];
        #pragma unroll
        for (int m = 16; m >= 1; m >>= 1) {
            s1 += __shfl_xor(s1, m);
            s2 += __shfl_xor(s2, m);
        }
        float mu  = s1 * (1.0f / 128.0f);
        float var = s2 * (1.0f / 128.0f) - mu * mu;
        float rstd = rsqrtf(var + LN_EPS);
        int gn = n0 + ng * 4 + i;
        if (gn < N_NODES) {
            float4 o;
            o.x = fmaxf(0.f, gg[0] * (acc[i][0] - mu) * rstd + bb[0]);
            o.y = fmaxf(0.f, gg[1] * (acc[i][1] - mu) * rstd + bb[1]);
            o.z = fmaxf(0.f, gg[2] * (acc[i][2] - mu) * rstd + bb[2]);
            o.w = fmaxf(0.f, gg[3] * (acc[i][3] - mu) * rstd + bb[3]);
            *(float4*)(&hout[(size_t)gn * 128 + f4 * 4]) = o;
        }
    }
}

// ---------------------------------------------------------------------------
// graph start offsets from sorted batch
__global__ void starts_kernel(const int* __restrict__ batch, int* __restrict__ starts)
{
    int i = blockIdx.x * blockDim.x + threadIdx.x;
    if (i >= N_NODES) return;
    int b = batch[i];
    int pb = (i == 0) ? -1 : batch[i - 1];
    for (int g = pb + 1; g <= b; ++g) starts[g] = i;
    if (i == N_NODES - 1)
        for (int g = b + 1; g <= N_GRAPHS; ++g) starts[g] = N_NODES;
}

// per-graph mean+max pooling -> pooled [G, 256]
__global__ __launch_bounds__(128) void pool_kernel(const float* __restrict__ h,
                                                   const int* __restrict__ starts,
                                                   float* __restrict__ pooled)
{
    int g = blockIdx.x;
    int j = threadIdx.x;
    int s0 = starts[g], s1 = starts[g + 1];
    float sum = 0.f, mx = -INFINITY;
    for (int n = s0; n < s1; ++n) {
        float v = h[(size_t)n * 128 + j];
        sum += v;
        mx = fmaxf(mx, v);
    }
    int c = s1 - s0;
    pooled[g * 256 + j]       = sum / fmaxf((float)c, 1.0f);
    pooled[g * 256 + 128 + j] = (c > 0) ? mx : 0.0f;
}

// head: out[g][o] = blin[o] + pooled[g] . Wlin[o]
__global__ __launch_bounds__(256) void head_kernel(const float* __restrict__ pooled,
                                                   const float* __restrict__ Wlin,
                                                   const float* __restrict__ blin,
                                                   float* __restrict__ out)
{
    int g = blockIdx.x;
    __shared__ float p[256];
    p[threadIdx.x] = pooled[g * 256 + threadIdx.x];
    __syncthreads();
    if (threadIdx.x < 10) {
        const float* w = Wlin + threadIdx.x * 256;
        float acc = blin[threadIdx.x];
        for (int k = 0; k < 256; ++k) acc += p[k] * w[k];
        out[g * 10 + threadIdx.x] = acc;
    }
}

// ---------------------------------------------------------------------------
extern "C" void kernel_launch(void* const* d_in, const int* in_sizes, int n_in,
                              void* d_out, int out_size, void* d_ws, size_t ws_size,
                              hipStream_t stream)
{
    const float* x      = (const float*)d_in[0];
    const float* xdims  = (const float*)d_in[1];
    const int*   stt    = (const int*)d_in[2];
    const int*   eidx   = (const int*)d_in[3];
    const int*   batch  = (const int*)d_in[4];
    const float* st_emb = (const float*)d_in[5];
    const float* Wl1 = (const float*)d_in[6];
    const float* bl1 = (const float*)d_in[7];
    const float* Wr1 = (const float*)d_in[8];
    const float* g1  = (const float*)d_in[9];
    const float* be1 = (const float*)d_in[10];
    const float* Wl2 = (const float*)d_in[11];
    const float* bl2 = (const float*)d_in[12];
    const float* Wr2 = (const float*)d_in[13];
    const float* g2  = (const float*)d_in[14];
    const float* be2 = (const float*)d_in[15];
    const float* Wlin = (const float*)d_in[16];
    const float* blin = (const float*)d_in[17];
    float* out = (float*)d_out;

    const int* esrc_in = eidx;
    const int* edst_in = eidx + N_EDGES;

    // workspace carve-up (256B aligned)
    char* ws = (char*)d_ws;
    size_t o = 0;
    auto carve = [&](size_t bytes) { void* p = ws + o; o = (o + bytes + 255) & ~(size_t)255; return p; };
    float* h0f   = (float*)carve((size_t)N_NODES * 44 * 4);
    float* h1f   = (float*)carve((size_t)N_NODES * 128 * 4);
    float* h2f   = (float*)carve((size_t)N_NODES * 128 * 4);
    float* meanf = (float*)carve((size_t)N_NODES * 128 * 4);
    int*   cnt   = (int*)carve((size_t)N_NODES * 4);
    int*   offs  = (int*)carve((size_t)(N_NODES + 1) * 4);
    int*   pos   = (int*)carve((size_t)N_NODES * 4);
    int*   esrc  = (int*)carve((size_t)N_EDGES * 4);
    float* pooled = (float*)carve((size_t)N_GRAPHS * 256 * 4);
    int*   starts = (int*)carve((size_t)(N_GRAPHS + 1) * 4);
    (void)ws_size;

    // ---- build h0
    h0_kernel<<<(N_NODES * 44 + 255) / 256, 256, 0, stream>>>(x, xdims, stt, st_emb, h0f);

    // ---- CSR by dst
    hipMemsetAsync(cnt, 0, (size_t)N_NODES * 4, stream);
    count_kernel<<<(N_EDGES + 255) / 256, 256, 0, stream>>>(edst_in, cnt);
    scan_kernel<<<1, 1024, 0, stream>>>(cnt, offs, N_NODES);
    copy_int_kernel<<<(N_NODES + 255) / 256, 256, 0, stream>>>(offs, pos, N_NODES);
    fill_kernel<<<(N_EDGES + 255) / 256, 256, 0, stream>>>(esrc_in, edst_in, pos, esrc);

    // ---- graph boundaries (batch sorted)
    starts_kernel<<<(N_NODES + 255) / 256, 256, 0, stream>>>(batch, starts);

    // ---- layer 1
    agg_kernel<44><<<N_NODES, 64, 0, stream>>>(h0f, offs, esrc, meanf);
    layer_kernel<44><<<(N_NODES + 31) / 32, 256, 0, stream>>>(h0f, meanf, Wl1, bl1, Wr1, g1, be1, h1f);

    // ---- layer 2
    agg_kernel<128><<<N_NODES, 128, 0, stream>>>(h1f, offs, esrc, meanf);
    layer_kernel<128><<<(N_NODES + 31) / 32, 256, 0, stream>>>(h1f, meanf, Wl2, bl2, Wr2, g2, be2, h2f);

    // ---- pooling + head
    pool_kernel<<<N_GRAPHS, 128, 0, stream>>>(h2f, starts, pooled);
    head_kernel<<<N_GRAPHS, 256, 0, stream>>>(pooled, Wlin, blin, out);
}

// Round 2
// 365.827 us; speedup vs baseline: 1.5561x; 1.5561x over previous
//
#include <hip/hip_runtime.h>
#include <hip/hip_bf16.h>
#include <math.h>

#define N_NODES 50000
#define N_EDGES 600000
#define N_GRAPHS 512
#define LN_EPS 1e-5f

typedef short bf16x8 __attribute__((ext_vector_type(8)));
typedef float f32x4 __attribute__((ext_vector_type(4)));

__device__ __forceinline__ unsigned short f2bf(float f) {
    unsigned int x = __float_as_uint(f);
    return (unsigned short)((x + 0x7fffu + ((x >> 16) & 1u)) >> 16);
}
__device__ __forceinline__ float bflo(unsigned int u) { return __uint_as_float(u << 16); }
__device__ __forceinline__ float bfhi(unsigned int u) { return __uint_as_float(u & 0xffff0000u); }

// ---------------------------------------------------------------------------
// h0 -> Xcat1 cols [0,44) as bf16 (row stride 96)
__global__ void h0_kernel(const float* __restrict__ x,
                          const float* __restrict__ xdims,
                          const int* __restrict__ stt,
                          const float* __restrict__ st_emb,
                          unsigned short* __restrict__ Xc1)
{
    int idx = blockIdx.x * 256 + threadIdx.x;
    if (idx >= N_NODES * 44) return;
    int n = idx / 44;
    int c = idx - n * 44;
    float v;
    if (c < 29)       v = x[n * 29 + c];
    else if (c < 32)  v = xdims[n * 3 + (c - 29)];
    else              v = st_emb[stt[n] * 12 + (c - 32)];
    Xc1[(size_t)n * 96 + c] = f2bf(v);
}

// ---------------------------------------------------------------------------
// CSR build by dst
__global__ void count_kernel(const int* __restrict__ dst, int* __restrict__ cnt)
{
    int e = blockIdx.x * blockDim.x + threadIdx.x;
    if (e < N_EDGES) atomicAdd(&cnt[dst[e]], 1);
}

__global__ void scan_kernel(const int* __restrict__ cnt, int* __restrict__ offs, int n)
{
    __shared__ int s[1024];
    __shared__ int carry_sh;
    if (threadIdx.x == 0) carry_sh = 0;
    __syncthreads();
    for (int base = 0; base < n; base += 1024) {
        int i = base + (int)threadIdx.x;
        int v = (i < n) ? cnt[i] : 0;
        s[threadIdx.x] = v;
        __syncthreads();
        #pragma unroll
        for (int d = 1; d < 1024; d <<= 1) {
            int t = (threadIdx.x >= (unsigned)d) ? s[threadIdx.x - d] : 0;
            __syncthreads();
            s[threadIdx.x] += t;
            __syncthreads();
        }
        int incl = s[threadIdx.x];
        int carry = carry_sh;
        if (i < n) offs[i] = carry + incl - v;
        __syncthreads();
        if (threadIdx.x == 1023) carry_sh = carry + s[1023];
        __syncthreads();
    }
    if (threadIdx.x == 0) offs[n] = carry_sh;
}

__global__ void copy_int_kernel(const int* __restrict__ src, int* __restrict__ dstp, int n)
{
    int i = blockIdx.x * blockDim.x + threadIdx.x;
    if (i < n) dstp[i] = src[i];
}

__global__ void fill_kernel(const int* __restrict__ esrc_in, const int* __restrict__ edst_in,
                            int* __restrict__ pos, int* __restrict__ esrc_out)
{
    int e = blockIdx.x * blockDim.x + threadIdx.x;
    if (e < N_EDGES) {
        int p = atomicAdd(&pos[edst_in[e]], 1);
        esrc_out[p] = esrc_in[e];
    }
}

// ---------------------------------------------------------------------------
// agg1: gather Xcat1 cols[0,44) (bf16), mean -> Xcat1 cols[44,88), pad [88,96)=0
// one wave per node, 4 nodes per block
__global__ __launch_bounds__(256) void agg1_kernel(const int* __restrict__ offs,
                                                   const int* __restrict__ esrc,
                                                   unsigned short* __restrict__ Xc)
{
    int n = blockIdx.x * 4 + (threadIdx.x >> 6);
    int j = threadIdx.x & 63;
    if (n >= N_NODES) return;
    int s0 = offs[n], s1 = offs[n + 1];
    float a0 = 0.f, a1 = 0.f;
    const unsigned int* base = (const unsigned int*)Xc;   // row stride 48 uints
    if (j < 22) {
        for (int e = s0; e < s1; ++e) {
            unsigned int u = base[(size_t)esrc[e] * 48 + j];
            a0 += bflo(u);
            a1 += bfhi(u);
        }
    }
    float inv = (s1 > s0) ? 1.f / (float)(s1 - s0) : 0.f;
    unsigned int* bw = (unsigned int*)Xc;
    if (j < 22) {
        unsigned int p = (unsigned int)f2bf(a0 * inv) | ((unsigned int)f2bf(a1 * inv) << 16);
        bw[(size_t)n * 48 + 22 + j] = p;
    } else if (j < 26) {
        bw[(size_t)n * 48 + 22 + j] = 0u;   // cols 88..95 zero pad
    }
}

// agg2: gather Xcat2 cols[0,128) (bf16), mean -> Xcat2 cols[128,256)
__global__ __launch_bounds__(256) void agg2_kernel(const int* __restrict__ offs,
                                                   const int* __restrict__ esrc,
                                                   unsigned short* __restrict__ Xc)
{
    int n = blockIdx.x * 4 + (threadIdx.x >> 6);
    int j = threadIdx.x & 63;
    if (n >= N_NODES) return;
    int s0 = offs[n], s1 = offs[n + 1];
    float a0 = 0.f, a1 = 0.f;
    const unsigned int* base = (const unsigned int*)Xc;   // row stride 128 uints
    for (int e = s0; e < s1; ++e) {
        unsigned int u = base[(size_t)esrc[e] * 128 + j];
        a0 += bflo(u);
        a1 += bfhi(u);
    }
    float inv = (s1 > s0) ? 1.f / (float)(s1 - s0) : 0.f;
    unsigned int p = (unsigned int)f2bf(a0 * inv) | ((unsigned int)f2bf(a1 * inv) << 16);
    ((unsigned int*)Xc)[(size_t)n * 128 + 64 + j] = p;
}

// ---------------------------------------------------------------------------
// weight concat -> bf16 : Wcat row f = [Wr[f,:] | Wl[f,:] | pad]
__global__ void wcat1_kernel(const float* __restrict__ Wl, const float* __restrict__ Wr,
                             unsigned short* __restrict__ Wc)
{
    int i = blockIdx.x * 256 + threadIdx.x;
    if (i >= 128 * 96) return;
    int f = i / 96, k = i - f * 96;
    float v = (k < 44) ? Wr[f * 44 + k] : ((k < 88) ? Wl[f * 44 + (k - 44)] : 0.f);
    Wc[i] = f2bf(v);
}

__global__ void wcat2_kernel(const float* __restrict__ Wl, const float* __restrict__ Wr,
                             unsigned short* __restrict__ Wc)
{
    int i = blockIdx.x * 256 + threadIdx.x;
    if (i >= 128 * 256) return;
    int f = i >> 8, k = i & 255;
    float v = (k < 128) ? Wr[f * 128 + k] : Wl[f * 128 + (k - 128)];
    Wc[i] = f2bf(v);
}

// ---------------------------------------------------------------------------
// fused MFMA layer: Out[node][f] = relu(LN(Xcat @ Wcat^T + bl)) as bf16
// block = 4 waves, each wave 32 nodes x 128 feats; K-loop over KPAD/32
template <int KPAD>
__global__ __launch_bounds__(256) void mfma_layer_kernel(
    const unsigned short* __restrict__ X, const unsigned short* __restrict__ W,
    const float* __restrict__ bl, const float* __restrict__ g,
    const float* __restrict__ beta,
    unsigned short* __restrict__ Out, int outStride)
{
    const int lane = threadIdx.x & 63;
    const int wv   = threadIdx.x >> 6;
    const int l15  = lane & 15;
    const int l4   = lane >> 4;
    const int row0 = blockIdx.x * 128 + wv * 32;

    int rA0 = row0 + l15;       if (rA0 > N_NODES - 1) rA0 = N_NODES - 1;
    int rA1 = row0 + 16 + l15;  if (rA1 > N_NODES - 1) rA1 = N_NODES - 1;

    f32x4 acc[2][8];
    #pragma unroll
    for (int m = 0; m < 2; ++m)
        #pragma unroll
        for (int n = 0; n < 8; ++n) acc[m][n] = (f32x4){0.f, 0.f, 0.f, 0.f};

    const int kb = l4 * 8;
    #pragma unroll
    for (int ks = 0; ks < KPAD / 32; ++ks) {
        const int k = ks * 32 + kb;
        bf16x8 a0 = *(const bf16x8*)(X + (size_t)rA0 * KPAD + k);
        bf16x8 a1 = *(const bf16x8*)(X + (size_t)rA1 * KPAD + k);
        #pragma unroll
        for (int ni = 0; ni < 8; ++ni) {
            bf16x8 b = *(const bf16x8*)(W + (size_t)(ni * 16 + l15) * KPAD + k);
            acc[0][ni] = __builtin_amdgcn_mfma_f32_16x16x32_bf16(a0, b, acc[0][ni], 0, 0, 0);
            acc[1][ni] = __builtin_amdgcn_mfma_f32_16x16x32_bf16(a1, b, acc[1][ni], 0, 0, 0);
        }
    }

    float blv[8], gv[8], bev[8];
    #pragma unroll
    for (int ni = 0; ni < 8; ++ni) {
        int f = ni * 16 + l15;
        blv[ni] = bl[f]; gv[ni] = g[f]; bev[ni] = beta[f];
    }

    #pragma unroll
    for (int mi = 0; mi < 2; ++mi) {
        #pragma unroll
        for (int r = 0; r < 4; ++r) {
            float v[8];
            float s1 = 0.f, s2 = 0.f;
            #pragma unroll
            for (int ni = 0; ni < 8; ++ni) {
                float t = acc[mi][ni][r] + blv[ni];
                v[ni] = t; s1 += t; s2 += t * t;
            }
            #pragma unroll
            for (int m = 8; m >= 1; m >>= 1) {
                s1 += __shfl_xor(s1, m);
                s2 += __shfl_xor(s2, m);
            }
            float mu   = s1 * (1.f / 128.f);
            float var  = s2 * (1.f / 128.f) - mu * mu;
            float rstd = rsqrtf(var + LN_EPS);
            int node = row0 + mi * 16 + l4 * 4 + r;
            if (node < N_NODES) {
                #pragma unroll
                for (int ni = 0; ni < 8; ++ni) {
                    float o = gv[ni] * (v[ni] - mu) * rstd + bev[ni];
                    o = fmaxf(o, 0.f);
                    Out[(size_t)node * outStride + ni * 16 + l15] = f2bf(o);
                }
            }
        }
    }
}

// ---------------------------------------------------------------------------
__global__ void starts_kernel(const int* __restrict__ batch, int* __restrict__ starts)
{
    int i = blockIdx.x * blockDim.x + threadIdx.x;
    if (i >= N_NODES) return;
    int b = batch[i];
    int pb = (i == 0) ? -1 : batch[i - 1];
    for (int g = pb + 1; g <= b; ++g) starts[g] = i;
    if (i == N_NODES - 1)
        for (int g = b + 1; g <= N_GRAPHS; ++g) starts[g] = N_NODES;
}

__global__ __launch_bounds__(128) void pool_kernel(const unsigned short* __restrict__ h2,
                                                   const int* __restrict__ starts,
                                                   float* __restrict__ pooled)
{
    int gph = blockIdx.x;
    int j = threadIdx.x;
    int s0 = starts[gph], s1 = starts[gph + 1];
    float sum = 0.f, mx = -INFINITY;
    for (int n = s0; n < s1; ++n) {
        float v = __uint_as_float(((unsigned int)h2[(size_t)n * 128 + j]) << 16);
        sum += v;
        mx = fmaxf(mx, v);
    }
    int c = s1 - s0;
    pooled[gph * 256 + j]       = sum / fmaxf((float)c, 1.f);
    pooled[gph * 256 + 128 + j] = (c > 0) ? mx : 0.f;
}

__global__ __launch_bounds__(256) void head_kernel(const float* __restrict__ pooled,
                                                   const float* __restrict__ Wlin,
                                                   const float* __restrict__ blin,
                                                   float* __restrict__ out)
{
    int gph = blockIdx.x;
    __shared__ float p[256];
    p[threadIdx.x] = pooled[gph * 256 + threadIdx.x];
    __syncthreads();
    if (threadIdx.x < 10) {
        const float* w = Wlin + threadIdx.x * 256;
        float acc = blin[threadIdx.x];
        for (int k = 0; k < 256; ++k) acc += p[k] * w[k];
        out[gph * 10 + threadIdx.x] = acc;
    }
}

// ---------------------------------------------------------------------------
extern "C" void kernel_launch(void* const* d_in, const int* in_sizes, int n_in,
                              void* d_out, int out_size, void* d_ws, size_t ws_size,
                              hipStream_t stream)
{
    const float* x      = (const float*)d_in[0];
    const float* xdims  = (const float*)d_in[1];
    const int*   stt    = (const int*)d_in[2];
    const int*   eidx   = (const int*)d_in[3];
    const int*   batch  = (const int*)d_in[4];
    const float* st_emb = (const float*)d_in[5];
    const float* Wl1 = (const float*)d_in[6];
    const float* bl1 = (const float*)d_in[7];
    const float* Wr1 = (const float*)d_in[8];
    const float* g1  = (const float*)d_in[9];
    const float* be1 = (const float*)d_in[10];
    const float* Wl2 = (const float*)d_in[11];
    const float* bl2 = (const float*)d_in[12];
    const float* Wr2 = (const float*)d_in[13];
    const float* g2  = (const float*)d_in[14];
    const float* be2 = (const float*)d_in[15];
    const float* Wlin = (const float*)d_in[16];
    const float* blin = (const float*)d_in[17];
    float* out = (float*)d_out;

    const int* esrc_in = eidx;
    const int* edst_in = eidx + N_EDGES;

    char* ws = (char*)d_ws;
    size_t o = 0;
    auto carve = [&](size_t bytes) { void* p = ws + o; o = (o + bytes + 255) & ~(size_t)255; return p; };
    unsigned short* Xc1  = (unsigned short*)carve((size_t)N_NODES * 96 * 2);
    unsigned short* Xc2  = (unsigned short*)carve((size_t)N_NODES * 256 * 2);
    unsigned short* h2bf = (unsigned short*)carve((size_t)N_NODES * 128 * 2);
    unsigned short* Wc1  = (unsigned short*)carve((size_t)128 * 96 * 2);
    unsigned short* Wc2  = (unsigned short*)carve((size_t)128 * 256 * 2);
    int*   cnt    = (int*)carve((size_t)N_NODES * 4);
    int*   offs   = (int*)carve((size_t)(N_NODES + 1) * 4);
    int*   pos    = (int*)carve((size_t)N_NODES * 4);
    int*   esrc   = (int*)carve((size_t)N_EDGES * 4);
    float* pooled = (float*)carve((size_t)N_GRAPHS * 256 * 4);
    int*   starts = (int*)carve((size_t)(N_GRAPHS + 1) * 4);
    (void)ws_size;

    // weights -> bf16 concat
    wcat1_kernel<<<(128 * 96 + 255) / 256, 256, 0, stream>>>(Wl1, Wr1, Wc1);
    wcat2_kernel<<<(128 * 256 + 255) / 256, 256, 0, stream>>>(Wl2, Wr2, Wc2);

    // h0 -> Xcat1[:,0:44]
    h0_kernel<<<(N_NODES * 44 + 255) / 256, 256, 0, stream>>>(x, xdims, stt, st_emb, Xc1);

    // CSR by dst
    hipMemsetAsync(cnt, 0, (size_t)N_NODES * 4, stream);
    count_kernel<<<(N_EDGES + 255) / 256, 256, 0, stream>>>(edst_in, cnt);
    scan_kernel<<<1, 1024, 0, stream>>>(cnt, offs, N_NODES);
    copy_int_kernel<<<(N_NODES + 255) / 256, 256, 0, stream>>>(offs, pos, N_NODES);
    fill_kernel<<<(N_EDGES + 255) / 256, 256, 0, stream>>>(esrc_in, edst_in, pos, esrc);

    starts_kernel<<<(N_NODES + 255) / 256, 256, 0, stream>>>(batch, starts);

    // layer 1
    agg1_kernel<<<(N_NODES + 3) / 4, 256, 0, stream>>>(offs, esrc, Xc1);
    mfma_layer_kernel<96><<<(N_NODES + 127) / 128, 256, 0, stream>>>(
        Xc1, Wc1, bl1, g1, be1, Xc2, 256);

    // layer 2
    agg2_kernel<<<(N_NODES + 3) / 4, 256, 0, stream>>>(offs, esrc, Xc2);
    mfma_layer_kernel<256><<<(N_NODES + 127) / 128, 256, 0, stream>>>(
        Xc2, Wc2, bl2, g2, be2, h2bf, 128);

    // pooling + head
    pool_kernel<<<N_GRAPHS, 128, 0, stream>>>(h2bf, starts, pooled);
    head_kernel<<<N_GRAPHS, 256, 0, stream>>>(pooled, Wlin, blin, out);
}

// Round 3
// 260.997 us; speedup vs baseline: 2.1811x; 1.4017x over previous
//
#include <hip/hip_runtime.h>
#include <hip/hip_bf16.h>
#include <math.h>

#define N_NODES 50000
#define N_EDGES 600000
#define N_GRAPHS 512
#define LN_EPS 1e-5f
#define NB_SCAN ((N_NODES + 255) / 256)

typedef short bf16x8 __attribute__((ext_vector_type(8)));
typedef float f32x4 __attribute__((ext_vector_type(4)));

__device__ __forceinline__ unsigned short f2bf(float f) {
    unsigned int x = __float_as_uint(f);
    return (unsigned short)((x + 0x7fffu + ((x >> 16) & 1u)) >> 16);
}
__device__ __forceinline__ float bflo(unsigned int u) { return __uint_as_float(u << 16); }
__device__ __forceinline__ float bfhi(unsigned int u) { return __uint_as_float(u & 0xffff0000u); }

// ---------------------------------------------------------------------------
// h0 -> Xcat1 cols [0,44) as bf16 (row stride 96)
__global__ void h0_kernel(const float* __restrict__ x,
                          const float* __restrict__ xdims,
                          const int* __restrict__ stt,
                          const float* __restrict__ st_emb,
                          unsigned short* __restrict__ Xc1)
{
    int idx = blockIdx.x * 256 + threadIdx.x;
    if (idx >= N_NODES * 44) return;
    int n = idx / 44;
    int c = idx - n * 44;
    float v;
    if (c < 29)       v = x[n * 29 + c];
    else if (c < 32)  v = xdims[n * 3 + (c - 29)];
    else              v = st_emb[stt[n] * 12 + (c - 32)];
    Xc1[(size_t)n * 96 + c] = f2bf(v);
}

// ---------------------------------------------------------------------------
// CSR build by dst
__global__ void count_kernel(const int* __restrict__ dst, int* __restrict__ cnt)
{
    int e = blockIdx.x * blockDim.x + threadIdx.x;
    if (e < N_EDGES) atomicAdd(&cnt[dst[e]], 1);
}

// hierarchical scan: A) per-block sums
__global__ __launch_bounds__(256) void scan_blocksum_kernel(const int* __restrict__ cnt,
                                                            int* __restrict__ bsum)
{
    __shared__ int lds[4];
    int i = blockIdx.x * 256 + threadIdx.x;
    int v = (i < N_NODES) ? cnt[i] : 0;
    #pragma unroll
    for (int d = 32; d >= 1; d >>= 1) v += __shfl_down(v, d);
    int lane = threadIdx.x & 63, wv = threadIdx.x >> 6;
    if (lane == 0) lds[wv] = v;
    __syncthreads();
    if (threadIdx.x == 0) bsum[blockIdx.x] = lds[0] + lds[1] + lds[2] + lds[3];
}

// B) scan the NB_SCAN block sums (single block)
__global__ __launch_bounds__(256) void scan_bsum_kernel(const int* __restrict__ bsum,
                                                        int* __restrict__ boffs,
                                                        int* __restrict__ offs)
{
    __shared__ int lds[4];
    int i = threadIdx.x;
    int v = (i < NB_SCAN) ? bsum[i] : 0;
    int lane = i & 63, wv = i >> 6;
    int incl = v;
    #pragma unroll
    for (int d = 1; d < 64; d <<= 1) {
        int t = __shfl_up(incl, d);
        if (lane >= d) incl += t;
    }
    if (lane == 63) lds[wv] = incl;
    __syncthreads();
    int add = 0;
    #pragma unroll
    for (int w = 0; w < 4; ++w) if (w < wv) add += lds[w];
    if (i < NB_SCAN) boffs[i] = add + incl - v;
    if (i == 0) offs[N_NODES] = N_EDGES;
}

// C) per-element exclusive scan; writes offs and pos
__global__ __launch_bounds__(256) void scan_final_kernel(const int* __restrict__ cnt,
                                                         const int* __restrict__ boffs,
                                                         int* __restrict__ offs,
                                                         int* __restrict__ pos)
{
    __shared__ int lds[4];
    int i = blockIdx.x * 256 + threadIdx.x;
    int v = (i < N_NODES) ? cnt[i] : 0;
    int lane = threadIdx.x & 63, wv = threadIdx.x >> 6;
    int incl = v;
    #pragma unroll
    for (int d = 1; d < 64; d <<= 1) {
        int t = __shfl_up(incl, d);
        if (lane >= d) incl += t;
    }
    if (lane == 63) lds[wv] = incl;
    __syncthreads();
    int add = boffs[blockIdx.x];
    #pragma unroll
    for (int w = 0; w < 4; ++w) if (w < wv) add += lds[w];
    if (i < N_NODES) { int e = add + incl - v; offs[i] = e; pos[i] = e; }
}

__global__ void fill_kernel(const int* __restrict__ esrc_in, const int* __restrict__ edst_in,
                            int* __restrict__ pos, int* __restrict__ esrc_out)
{
    int e = blockIdx.x * blockDim.x + threadIdx.x;
    if (e < N_EDGES) {
        int p = atomicAdd(&pos[edst_in[e]], 1);
        esrc_out[p] = esrc_in[e];
    }
}

// ---------------------------------------------------------------------------
// agg1: gather Xcat1 cols[0,44) (bf16), mean -> cols[44,88), pad [88,96)=0
// half-wave (32 lanes) per node, 8 nodes per block
__global__ __launch_bounds__(256) void agg1_kernel(const int* __restrict__ offs,
                                                   const int* __restrict__ esrc,
                                                   unsigned short* __restrict__ Xc)
{
    int n = blockIdx.x * 8 + (threadIdx.x >> 5);
    int j = threadIdx.x & 31;
    if (n >= N_NODES) return;
    int s0 = offs[n], s1 = offs[n + 1];
    float a0 = 0.f, a1 = 0.f;
    const unsigned int* base = (const unsigned int*)Xc;   // row stride 48 uints
    if (j < 22) {
        for (int e = s0; e < s1; ++e) {
            unsigned int u = base[(size_t)esrc[e] * 48 + j];
            a0 += bflo(u);
            a1 += bfhi(u);
        }
    }
    float inv = (s1 > s0) ? 1.f / (float)(s1 - s0) : 0.f;
    unsigned int* bw = (unsigned int*)Xc;
    if (j < 22) {
        unsigned int p = (unsigned int)f2bf(a0 * inv) | ((unsigned int)f2bf(a1 * inv) << 16);
        bw[(size_t)n * 48 + 22 + j] = p;
    } else if (j < 26) {
        bw[(size_t)n * 48 + 22 + j] = 0u;   // cols 88..95 zero pad
    }
}

// agg2: gather Xcat2 cols[0,128) (bf16), mean -> Xcat2 cols[128,256)
__global__ __launch_bounds__(256) void agg2_kernel(const int* __restrict__ offs,
                                                   const int* __restrict__ esrc,
                                                   unsigned short* __restrict__ Xc)
{
    int n = blockIdx.x * 4 + (threadIdx.x >> 6);
    int j = threadIdx.x & 63;
    if (n >= N_NODES) return;
    int s0 = offs[n], s1 = offs[n + 1];
    float a0 = 0.f, a1 = 0.f;
    const unsigned int* base = (const unsigned int*)Xc;   // row stride 128 uints
    for (int e = s0; e < s1; ++e) {
        unsigned int u = base[(size_t)esrc[e] * 128 + j];
        a0 += bflo(u);
        a1 += bfhi(u);
    }
    float inv = (s1 > s0) ? 1.f / (float)(s1 - s0) : 0.f;
    unsigned int p = (unsigned int)f2bf(a0 * inv) | ((unsigned int)f2bf(a1 * inv) << 16);
    ((unsigned int*)Xc)[(size_t)n * 128 + 64 + j] = p;
}

// ---------------------------------------------------------------------------
// weight concat -> bf16 : Wcat row f = [Wr[f,:] | Wl[f,:] | pad]
__global__ void wcat1_kernel(const float* __restrict__ Wl, const float* __restrict__ Wr,
                             unsigned short* __restrict__ Wc)
{
    int i = blockIdx.x * 256 + threadIdx.x;
    if (i >= 128 * 96) return;
    int f = i / 96, k = i - f * 96;
    float v = (k < 44) ? Wr[f * 44 + k] : ((k < 88) ? Wl[f * 44 + (k - 44)] : 0.f);
    Wc[i] = f2bf(v);
}

__global__ void wcat2_kernel(const float* __restrict__ Wl, const float* __restrict__ Wr,
                             unsigned short* __restrict__ Wc)
{
    int i = blockIdx.x * 256 + threadIdx.x;
    if (i >= 128 * 256) return;
    int f = i >> 8, k = i & 255;
    float v = (k < 128) ? Wr[f * 128 + k] : Wl[f * 128 + (k - 128)];
    Wc[i] = f2bf(v);
}

// ---------------------------------------------------------------------------
// fused MFMA layer: Out[node][f] = relu(LN(Xcat @ Wcat^T + bl)) as bf16
template <int KPAD>
__global__ __launch_bounds__(256) void mfma_layer_kernel(
    const unsigned short* __restrict__ X, const unsigned short* __restrict__ W,
    const float* __restrict__ bl, const float* __restrict__ g,
    const float* __restrict__ beta,
    unsigned short* __restrict__ Out, int outStride)
{
    const int lane = threadIdx.x & 63;
    const int wv   = threadIdx.x >> 6;
    const int l15  = lane & 15;
    const int l4   = lane >> 4;
    const int row0 = blockIdx.x * 128 + wv * 32;

    int rA0 = row0 + l15;       if (rA0 > N_NODES - 1) rA0 = N_NODES - 1;
    int rA1 = row0 + 16 + l15;  if (rA1 > N_NODES - 1) rA1 = N_NODES - 1;

    f32x4 acc[2][8];
    #pragma unroll
    for (int m = 0; m < 2; ++m)
        #pragma unroll
        for (int n = 0; n < 8; ++n) acc[m][n] = (f32x4){0.f, 0.f, 0.f, 0.f};

    const int kb = l4 * 8;
    #pragma unroll
    for (int ks = 0; ks < KPAD / 32; ++ks) {
        const int k = ks * 32 + kb;
        bf16x8 a0 = *(const bf16x8*)(X + (size_t)rA0 * KPAD + k);
        bf16x8 a1 = *(const bf16x8*)(X + (size_t)rA1 * KPAD + k);
        #pragma unroll
        for (int ni = 0; ni < 8; ++ni) {
            bf16x8 b = *(const bf16x8*)(W + (size_t)(ni * 16 + l15) * KPAD + k);
            acc[0][ni] = __builtin_amdgcn_mfma_f32_16x16x32_bf16(a0, b, acc[0][ni], 0, 0, 0);
            acc[1][ni] = __builtin_amdgcn_mfma_f32_16x16x32_bf16(a1, b, acc[1][ni], 0, 0, 0);
        }
    }

    float blv[8], gv[8], bev[8];
    #pragma unroll
    for (int ni = 0; ni < 8; ++ni) {
        int f = ni * 16 + l15;
        blv[ni] = bl[f]; gv[ni] = g[f]; bev[ni] = beta[f];
    }

    #pragma unroll
    for (int mi = 0; mi < 2; ++mi) {
        #pragma unroll
        for (int r = 0; r < 4; ++r) {
            float v[8];
            float s1 = 0.f, s2 = 0.f;
            #pragma unroll
            for (int ni = 0; ni < 8; ++ni) {
                float t = acc[mi][ni][r] + blv[ni];
                v[ni] = t; s1 += t; s2 += t * t;
            }
            #pragma unroll
            for (int m = 8; m >= 1; m >>= 1) {
                s1 += __shfl_xor(s1, m);
                s2 += __shfl_xor(s2, m);
            }
            float mu   = s1 * (1.f / 128.f);
            float var  = s2 * (1.f / 128.f) - mu * mu;
            float rstd = rsqrtf(var + LN_EPS);
            int node = row0 + mi * 16 + l4 * 4 + r;
            if (node < N_NODES) {
                #pragma unroll
                for (int ni = 0; ni < 8; ++ni) {
                    float o = gv[ni] * (v[ni] - mu) * rstd + bev[ni];
                    o = fmaxf(o, 0.f);
                    Out[(size_t)node * outStride + ni * 16 + l15] = f2bf(o);
                }
            }
        }
    }
}

// ---------------------------------------------------------------------------
__global__ void starts_kernel(const int* __restrict__ batch, int* __restrict__ starts)
{
    int i = blockIdx.x * blockDim.x + threadIdx.x;
    if (i >= N_NODES) return;
    int b = batch[i];
    int pb = (i == 0) ? -1 : batch[i - 1];
    for (int g = pb + 1; g <= b; ++g) starts[g] = i;
    if (i == N_NODES - 1)
        for (int g = b + 1; g <= N_GRAPHS; ++g) starts[g] = N_NODES;
}

__global__ __launch_bounds__(128) void pool_kernel(const unsigned short* __restrict__ h2,
                                                   const int* __restrict__ starts,
                                                   float* __restrict__ pooled)
{
    int gph = blockIdx.x;
    int j = threadIdx.x;
    int s0 = starts[gph], s1 = starts[gph + 1];
    float sum = 0.f, mx = -INFINITY;
    for (int n = s0; n < s1; ++n) {
        float v = __uint_as_float(((unsigned int)h2[(size_t)n * 128 + j]) << 16);
        sum += v;
        mx = fmaxf(mx, v);
    }
    int c = s1 - s0;
    pooled[gph * 256 + j]       = sum / fmaxf((float)c, 1.f);
    pooled[gph * 256 + 128 + j] = (c > 0) ? mx : 0.f;
}

__global__ __launch_bounds__(256) void head_kernel(const float* __restrict__ pooled,
                                                   const float* __restrict__ Wlin,
                                                   const float* __restrict__ blin,
                                                   float* __restrict__ out)
{
    int gph = blockIdx.x;
    __shared__ float p[256];
    p[threadIdx.x] = pooled[gph * 256 + threadIdx.x];
    __syncthreads();
    if (threadIdx.x < 10) {
        const float* w = Wlin + threadIdx.x * 256;
        float acc = blin[threadIdx.x];
        for (int k = 0; k < 256; ++k) acc += p[k] * w[k];
        out[gph * 10 + threadIdx.x] = acc;
    }
}

// ---------------------------------------------------------------------------
extern "C" void kernel_launch(void* const* d_in, const int* in_sizes, int n_in,
                              void* d_out, int out_size, void* d_ws, size_t ws_size,
                              hipStream_t stream)
{
    const float* x      = (const float*)d_in[0];
    const float* xdims  = (const float*)d_in[1];
    const int*   stt    = (const int*)d_in[2];
    const int*   eidx   = (const int*)d_in[3];
    const int*   batch  = (const int*)d_in[4];
    const float* st_emb = (const float*)d_in[5];
    const float* Wl1 = (const float*)d_in[6];
    const float* bl1 = (const float*)d_in[7];
    const float* Wr1 = (const float*)d_in[8];
    const float* g1  = (const float*)d_in[9];
    const float* be1 = (const float*)d_in[10];
    const float* Wl2 = (const float*)d_in[11];
    const float* bl2 = (const float*)d_in[12];
    const float* Wr2 = (const float*)d_in[13];
    const float* g2  = (const float*)d_in[14];
    const float* be2 = (const float*)d_in[15];
    const float* Wlin = (const float*)d_in[16];
    const float* blin = (const float*)d_in[17];
    float* out = (float*)d_out;

    const int* esrc_in = eidx;
    const int* edst_in = eidx + N_EDGES;

    char* ws = (char*)d_ws;
    size_t o = 0;
    auto carve = [&](size_t bytes) { void* p = ws + o; o = (o + bytes + 255) & ~(size_t)255; return p; };
    unsigned short* Xc1  = (unsigned short*)carve((size_t)N_NODES * 96 * 2);
    unsigned short* Xc2  = (unsigned short*)carve((size_t)N_NODES * 256 * 2);
    unsigned short* h2bf = (unsigned short*)carve((size_t)N_NODES * 128 * 2);
    unsigned short* Wc1  = (unsigned short*)carve((size_t)128 * 96 * 2);
    unsigned short* Wc2  = (unsigned short*)carve((size_t)128 * 256 * 2);
    int*   cnt    = (int*)carve((size_t)N_NODES * 4);
    int*   offs   = (int*)carve((size_t)(N_NODES + 1) * 4);
    int*   pos    = (int*)carve((size_t)N_NODES * 4);
    int*   esrc   = (int*)carve((size_t)N_EDGES * 4);
    int*   bsum   = (int*)carve((size_t)NB_SCAN * 4);
    int*   boffs  = (int*)carve((size_t)NB_SCAN * 4);
    float* pooled = (float*)carve((size_t)N_GRAPHS * 256 * 4);
    int*   starts = (int*)carve((size_t)(N_GRAPHS + 1) * 4);
    (void)ws_size;

    // weights -> bf16 concat
    wcat1_kernel<<<(128 * 96 + 255) / 256, 256, 0, stream>>>(Wl1, Wr1, Wc1);
    wcat2_kernel<<<(128 * 256 + 255) / 256, 256, 0, stream>>>(Wl2, Wr2, Wc2);

    // h0 -> Xcat1[:,0:44]
    h0_kernel<<<(N_NODES * 44 + 255) / 256, 256, 0, stream>>>(x, xdims, stt, st_emb, Xc1);

    // CSR by dst (hierarchical scan)
    hipMemsetAsync(cnt, 0, (size_t)N_NODES * 4, stream);
    count_kernel<<<(N_EDGES + 255) / 256, 256, 0, stream>>>(edst_in, cnt);
    scan_blocksum_kernel<<<NB_SCAN, 256, 0, stream>>>(cnt, bsum);
    scan_bsum_kernel<<<1, 256, 0, stream>>>(bsum, boffs, offs);
    scan_final_kernel<<<NB_SCAN, 256, 0, stream>>>(cnt, boffs, offs, pos);
    fill_kernel<<<(N_EDGES + 255) / 256, 256, 0, stream>>>(esrc_in, edst_in, pos, esrc);

    starts_kernel<<<(N_NODES + 255) / 256, 256, 0, stream>>>(batch, starts);

    // layer 1
    agg1_kernel<<<(N_NODES + 7) / 8, 256, 0, stream>>>(offs, esrc, Xc1);
    mfma_layer_kernel<96><<<(N_NODES + 127) / 128, 256, 0, stream>>>(
        Xc1, Wc1, bl1, g1, be1, Xc2, 256);

    // layer 2
    agg2_kernel<<<(N_NODES + 3) / 4, 256, 0, stream>>>(offs, esrc, Xc2);
    mfma_layer_kernel<256><<<(N_NODES + 127) / 128, 256, 0, stream>>>(
        Xc2, Wc2, bl2, g2, be2, h2bf, 128);

    // pooling + head
    pool_kernel<<<N_GRAPHS, 128, 0, stream>>>(h2bf, starts, pooled);
    head_kernel<<<N_GRAPHS, 256, 0, stream>>>(pooled, Wlin, blin, out);
}

// Round 4
// 209.761 us; speedup vs baseline: 2.7138x; 1.2443x over previous
//
#include <hip/hip_runtime.h>
#include <hip/hip_bf16.h>
#include <math.h>

#define N_NODES 50000
#define N_EDGES 600000
#define N_GRAPHS 512
#define LN_EPS 1e-5f
#define NB_SCAN ((N_NODES + 255) / 256)

typedef short bf16x8 __attribute__((ext_vector_type(8)));
typedef float f32x4 __attribute__((ext_vector_type(4)));

__device__ __forceinline__ unsigned short f2bf(float f) {
    unsigned int x = __float_as_uint(f);
    return (unsigned short)((x + 0x7fffu + ((x >> 16) & 1u)) >> 16);
}
__device__ __forceinline__ float bflo(unsigned int u) { return __uint_as_float(u << 16); }
__device__ __forceinline__ float bfhi(unsigned int u) { return __uint_as_float(u & 0xffff0000u); }

// ---------------------------------------------------------------------------
// h0 -> Xcat1 cols [0,48) as bf16 (row stride 96): cols 0..43 data, 44..47 zero
__global__ void h0_kernel(const float* __restrict__ x,
                          const float* __restrict__ xdims,
                          const int* __restrict__ stt,
                          const float* __restrict__ st_emb,
                          unsigned short* __restrict__ Xc1)
{
    int idx = blockIdx.x * 256 + threadIdx.x;
    if (idx >= N_NODES * 48) return;
    int n = idx / 48;
    int c = idx - n * 48;
    float v;
    if (c < 29)       v = x[n * 29 + c];
    else if (c < 32)  v = xdims[n * 3 + (c - 29)];
    else if (c < 44)  v = st_emb[stt[n] * 12 + (c - 32)];
    else              v = 0.f;
    Xc1[(size_t)n * 96 + c] = f2bf(v);
}

// ---------------------------------------------------------------------------
// CSR build by dst
__global__ void count_kernel(const int* __restrict__ dst, int* __restrict__ cnt)
{
    int e = blockIdx.x * blockDim.x + threadIdx.x;
    if (e < N_EDGES) atomicAdd(&cnt[dst[e]], 1);
}

__global__ __launch_bounds__(256) void scan_blocksum_kernel(const int* __restrict__ cnt,
                                                            int* __restrict__ bsum)
{
    __shared__ int lds[4];
    int i = blockIdx.x * 256 + threadIdx.x;
    int v = (i < N_NODES) ? cnt[i] : 0;
    #pragma unroll
    for (int d = 32; d >= 1; d >>= 1) v += __shfl_down(v, d);
    int lane = threadIdx.x & 63, wv = threadIdx.x >> 6;
    if (lane == 0) lds[wv] = v;
    __syncthreads();
    if (threadIdx.x == 0) bsum[blockIdx.x] = lds[0] + lds[1] + lds[2] + lds[3];
}

__global__ __launch_bounds__(256) void scan_bsum_kernel(const int* __restrict__ bsum,
                                                        int* __restrict__ boffs,
                                                        int* __restrict__ offs)
{
    __shared__ int lds[4];
    int i = threadIdx.x;
    int v = (i < NB_SCAN) ? bsum[i] : 0;
    int lane = i & 63, wv = i >> 6;
    int incl = v;
    #pragma unroll
    for (int d = 1; d < 64; d <<= 1) {
        int t = __shfl_up(incl, d);
        if (lane >= d) incl += t;
    }
    if (lane == 63) lds[wv] = incl;
    __syncthreads();
    int add = 0;
    #pragma unroll
    for (int w = 0; w < 4; ++w) if (w < wv) add += lds[w];
    if (i < NB_SCAN) boffs[i] = add + incl - v;
    if (i == 0) offs[N_NODES] = N_EDGES;
}

__global__ __launch_bounds__(256) void scan_final_kernel(const int* __restrict__ cnt,
                                                         const int* __restrict__ boffs,
                                                         int* __restrict__ offs,
                                                         int* __restrict__ pos)
{
    __shared__ int lds[4];
    int i = blockIdx.x * 256 + threadIdx.x;
    int v = (i < N_NODES) ? cnt[i] : 0;
    int lane = threadIdx.x & 63, wv = threadIdx.x >> 6;
    int incl = v;
    #pragma unroll
    for (int d = 1; d < 64; d <<= 1) {
        int t = __shfl_up(incl, d);
        if (lane >= d) incl += t;
    }
    if (lane == 63) lds[wv] = incl;
    __syncthreads();
    int add = boffs[blockIdx.x];
    #pragma unroll
    for (int w = 0; w < 4; ++w) if (w < wv) add += lds[w];
    if (i < N_NODES) { int e = add + incl - v; offs[i] = e; pos[i] = e; }
}

__global__ void fill_kernel(const int* __restrict__ esrc_in, const int* __restrict__ edst_in,
                            int* __restrict__ pos, int* __restrict__ esrc_out)
{
    int e = blockIdx.x * blockDim.x + threadIdx.x;
    if (e < N_EDGES) {
        int p = atomicAdd(&pos[edst_in[e]], 1);
        esrc_out[p] = esrc_in[e];
    }
}

// ---------------------------------------------------------------------------
// agg1: wave per node; 8-lane groups each gather one edge; uint4 loads.
// row = 12 uint4 (96 cols); gather slots 0..5 (cols 0..47), write slots 6..11
__global__ __launch_bounds__(256) void agg1_kernel(const int* __restrict__ offs,
                                                   const int* __restrict__ esrc,
                                                   unsigned short* __restrict__ Xc)
{
    int n = blockIdx.x * 4 + (threadIdx.x >> 6);
    if (n >= N_NODES) return;
    const int lane = threadIdx.x & 63;
    const int grp = lane >> 3;      // 0..7 edge slot
    const int sl  = lane & 7;       // 0..7 col chunk (active < 6)
    const bool act = sl < 6;
    int s0 = offs[n], s1 = offs[n + 1];
    float a0=0.f,a1=0.f,a2=0.f,a3=0.f,a4=0.f,a5=0.f,a6=0.f,a7=0.f;
    const uint4* base = (const uint4*)Xc;
    int e = s0;
    for (; e + 8 <= s1; e += 8) {
        int src = esrc[e + grp];
        if (act) {
            uint4 v = base[(size_t)src * 12 + sl];
            a0 += bflo(v.x); a1 += bfhi(v.x);
            a2 += bflo(v.y); a3 += bfhi(v.y);
            a4 += bflo(v.z); a5 += bfhi(v.z);
            a6 += bflo(v.w); a7 += bfhi(v.w);
        }
    }
    if (e + grp < s1) {
        int src = esrc[e + grp];
        if (act) {
            uint4 v = base[(size_t)src * 12 + sl];
            a0 += bflo(v.x); a1 += bfhi(v.x);
            a2 += bflo(v.y); a3 += bfhi(v.y);
            a4 += bflo(v.z); a5 += bfhi(v.z);
            a6 += bflo(v.w); a7 += bfhi(v.w);
        }
    }
    #pragma unroll
    for (int m = 8; m <= 32; m <<= 1) {
        a0 += __shfl_xor(a0, m); a1 += __shfl_xor(a1, m);
        a2 += __shfl_xor(a2, m); a3 += __shfl_xor(a3, m);
        a4 += __shfl_xor(a4, m); a5 += __shfl_xor(a5, m);
        a6 += __shfl_xor(a6, m); a7 += __shfl_xor(a7, m);
    }
    if (grp == 0 && act) {
        float inv = (s1 > s0) ? 1.f / (float)(s1 - s0) : 0.f;
        uint4 p;
        p.x = (unsigned int)f2bf(a0 * inv) | ((unsigned int)f2bf(a1 * inv) << 16);
        p.y = (unsigned int)f2bf(a2 * inv) | ((unsigned int)f2bf(a3 * inv) << 16);
        p.z = (unsigned int)f2bf(a4 * inv) | ((unsigned int)f2bf(a5 * inv) << 16);
        p.w = (unsigned int)f2bf(a6 * inv) | ((unsigned int)f2bf(a7 * inv) << 16);
        ((uint4*)Xc)[(size_t)n * 12 + 6 + sl] = p;
    }
}

// agg2: wave per node; 16-lane groups each gather one edge; uint4 loads.
// row = 32 uint4 (256 cols); gather slots 0..15, write slots 16..31
__global__ __launch_bounds__(256) void agg2_kernel(const int* __restrict__ offs,
                                                   const int* __restrict__ esrc,
                                                   unsigned short* __restrict__ Xc)
{
    int n = blockIdx.x * 4 + (threadIdx.x >> 6);
    if (n >= N_NODES) return;
    const int lane = threadIdx.x & 63;
    const int grp = lane >> 4;      // 0..3 edge slot
    const int sl  = lane & 15;      // 0..15 col chunk
    int s0 = offs[n], s1 = offs[n + 1];
    float a0=0.f,a1=0.f,a2=0.f,a3=0.f,a4=0.f,a5=0.f,a6=0.f,a7=0.f;
    const uint4* base = (const uint4*)Xc;
    int e = s0;
    for (; e + 8 <= s1; e += 8) {
        int srcA = esrc[e + grp];
        int srcB = esrc[e + 4 + grp];
        uint4 va = base[(size_t)srcA * 32 + sl];
        uint4 vb = base[(size_t)srcB * 32 + sl];
        a0 += bflo(va.x); a1 += bfhi(va.x);
        a2 += bflo(va.y); a3 += bfhi(va.y);
        a4 += bflo(va.z); a5 += bfhi(va.z);
        a6 += bflo(va.w); a7 += bfhi(va.w);
        a0 += bflo(vb.x); a1 += bfhi(vb.x);
        a2 += bflo(vb.y); a3 += bfhi(vb.y);
        a4 += bflo(vb.z); a5 += bfhi(vb.z);
        a6 += bflo(vb.w); a7 += bfhi(vb.w);
    }
    for (; e + 4 <= s1; e += 4) {
        int src = esrc[e + grp];
        uint4 v = base[(size_t)src * 32 + sl];
        a0 += bflo(v.x); a1 += bfhi(v.x);
        a2 += bflo(v.y); a3 += bfhi(v.y);
        a4 += bflo(v.z); a5 += bfhi(v.z);
        a6 += bflo(v.w); a7 += bfhi(v.w);
    }
    if (e + grp < s1) {
        int src = esrc[e + grp];
        uint4 v = base[(size_t)src * 32 + sl];
        a0 += bflo(v.x); a1 += bfhi(v.x);
        a2 += bflo(v.y); a3 += bfhi(v.y);
        a4 += bflo(v.z); a5 += bfhi(v.z);
        a6 += bflo(v.w); a7 += bfhi(v.w);
    }
    #pragma unroll
    for (int m = 16; m <= 32; m <<= 1) {
        a0 += __shfl_xor(a0, m); a1 += __shfl_xor(a1, m);
        a2 += __shfl_xor(a2, m); a3 += __shfl_xor(a3, m);
        a4 += __shfl_xor(a4, m); a5 += __shfl_xor(a5, m);
        a6 += __shfl_xor(a6, m); a7 += __shfl_xor(a7, m);
    }
    if (grp == 0) {
        float inv = (s1 > s0) ? 1.f / (float)(s1 - s0) : 0.f;
        uint4 p;
        p.x = (unsigned int)f2bf(a0 * inv) | ((unsigned int)f2bf(a1 * inv) << 16);
        p.y = (unsigned int)f2bf(a2 * inv) | ((unsigned int)f2bf(a3 * inv) << 16);
        p.z = (unsigned int)f2bf(a4 * inv) | ((unsigned int)f2bf(a5 * inv) << 16);
        p.w = (unsigned int)f2bf(a6 * inv) | ((unsigned int)f2bf(a7 * inv) << 16);
        ((uint4*)Xc)[(size_t)n * 32 + 16 + sl] = p;
    }
}

// ---------------------------------------------------------------------------
// weight concat -> bf16 : Wcat1 row f = [Wr[f,:44] | 0x4 | Wl[f,:44] | 0x4]
__global__ void wcat1_kernel(const float* __restrict__ Wl, const float* __restrict__ Wr,
                             unsigned short* __restrict__ Wc)
{
    int i = blockIdx.x * 256 + threadIdx.x;
    if (i >= 128 * 96) return;
    int f = i / 96, k = i - f * 96;
    float v;
    if (k < 44)       v = Wr[f * 44 + k];
    else if (k < 48)  v = 0.f;
    else if (k < 92)  v = Wl[f * 44 + (k - 48)];
    else              v = 0.f;
    Wc[i] = f2bf(v);
}

__global__ void wcat2_kernel(const float* __restrict__ Wl, const float* __restrict__ Wr,
                             unsigned short* __restrict__ Wc)
{
    int i = blockIdx.x * 256 + threadIdx.x;
    if (i >= 128 * 256) return;
    int f = i >> 8, k = i & 255;
    float v = (k < 128) ? Wr[f * 128 + k] : Wl[f * 128 + (k - 128)];
    Wc[i] = f2bf(v);
}

// ---------------------------------------------------------------------------
// fused MFMA layer: Out[node][f] = relu(LN(Xcat @ Wcat^T + bl)) as bf16
template <int KPAD>
__global__ __launch_bounds__(256) void mfma_layer_kernel(
    const unsigned short* __restrict__ X, const unsigned short* __restrict__ W,
    const float* __restrict__ bl, const float* __restrict__ g,
    const float* __restrict__ beta,
    unsigned short* __restrict__ Out, int outStride)
{
    const int lane = threadIdx.x & 63;
    const int wv   = threadIdx.x >> 6;
    const int l15  = lane & 15;
    const int l4   = lane >> 4;
    const int row0 = blockIdx.x * 128 + wv * 32;

    int rA0 = row0 + l15;       if (rA0 > N_NODES - 1) rA0 = N_NODES - 1;
    int rA1 = row0 + 16 + l15;  if (rA1 > N_NODES - 1) rA1 = N_NODES - 1;

    f32x4 acc[2][8];
    #pragma unroll
    for (int m = 0; m < 2; ++m)
        #pragma unroll
        for (int n = 0; n < 8; ++n) acc[m][n] = (f32x4){0.f, 0.f, 0.f, 0.f};

    const int kb = l4 * 8;
    #pragma unroll
    for (int ks = 0; ks < KPAD / 32; ++ks) {
        const int k = ks * 32 + kb;
        bf16x8 a0 = *(const bf16x8*)(X + (size_t)rA0 * KPAD + k);
        bf16x8 a1 = *(const bf16x8*)(X + (size_t)rA1 * KPAD + k);
        #pragma unroll
        for (int ni = 0; ni < 8; ++ni) {
            bf16x8 b = *(const bf16x8*)(W + (size_t)(ni * 16 + l15) * KPAD + k);
            acc[0][ni] = __builtin_amdgcn_mfma_f32_16x16x32_bf16(a0, b, acc[0][ni], 0, 0, 0);
            acc[1][ni] = __builtin_amdgcn_mfma_f32_16x16x32_bf16(a1, b, acc[1][ni], 0, 0, 0);
        }
    }

    float blv[8], gv[8], bev[8];
    #pragma unroll
    for (int ni = 0; ni < 8; ++ni) {
        int f = ni * 16 + l15;
        blv[ni] = bl[f]; gv[ni] = g[f]; bev[ni] = beta[f];
    }

    #pragma unroll
    for (int mi = 0; mi < 2; ++mi) {
        #pragma unroll
        for (int r = 0; r < 4; ++r) {
            float v[8];
            float s1 = 0.f, s2 = 0.f;
            #pragma unroll
            for (int ni = 0; ni < 8; ++ni) {
                float t = acc[mi][ni][r] + blv[ni];
                v[ni] = t; s1 += t; s2 += t * t;
            }
            #pragma unroll
            for (int m = 8; m >= 1; m >>= 1) {
                s1 += __shfl_xor(s1, m);
                s2 += __shfl_xor(s2, m);
            }
            float mu   = s1 * (1.f / 128.f);
            float var  = s2 * (1.f / 128.f) - mu * mu;
            float rstd = rsqrtf(var + LN_EPS);
            int node = row0 + mi * 16 + l4 * 4 + r;
            if (node < N_NODES) {
                #pragma unroll
                for (int ni = 0; ni < 8; ++ni) {
                    float o = gv[ni] * (v[ni] - mu) * rstd + bev[ni];
                    o = fmaxf(o, 0.f);
                    Out[(size_t)node * outStride + ni * 16 + l15] = f2bf(o);
                }
            }
        }
    }
}

// ---------------------------------------------------------------------------
__global__ void starts_kernel(const int* __restrict__ batch, int* __restrict__ starts)
{
    int i = blockIdx.x * blockDim.x + threadIdx.x;
    if (i >= N_NODES) return;
    int b = batch[i];
    int pb = (i == 0) ? -1 : batch[i - 1];
    for (int g = pb + 1; g <= b; ++g) starts[g] = i;
    if (i == N_NODES - 1)
        for (int g = b + 1; g <= N_GRAPHS; ++g) starts[g] = N_NODES;
}

__global__ __launch_bounds__(128) void pool_kernel(const unsigned short* __restrict__ h2,
                                                   const int* __restrict__ starts,
                                                   float* __restrict__ pooled)
{
    int gph = blockIdx.x;
    int j = threadIdx.x;
    int s0 = starts[gph], s1 = starts[gph + 1];
    float sum = 0.f, mx = -INFINITY;
    for (int n = s0; n < s1; ++n) {
        float v = __uint_as_float(((unsigned int)h2[(size_t)n * 128 + j]) << 16);
        sum += v;
        mx = fmaxf(mx, v);
    }
    int c = s1 - s0;
    pooled[gph * 256 + j]       = sum / fmaxf((float)c, 1.f);
    pooled[gph * 256 + 128 + j] = (c > 0) ? mx : 0.f;
}

__global__ __launch_bounds__(256) void head_kernel(const float* __restrict__ pooled,
                                                   const float* __restrict__ Wlin,
                                                   const float* __restrict__ blin,
                                                   float* __restrict__ out)
{
    int gph = blockIdx.x;
    __shared__ float p[256];
    p[threadIdx.x] = pooled[gph * 256 + threadIdx.x];
    __syncthreads();
    if (threadIdx.x < 10) {
        const float* w = Wlin + threadIdx.x * 256;
        float acc = blin[threadIdx.x];
        for (int k = 0; k < 256; ++k) acc += p[k] * w[k];
        out[gph * 10 + threadIdx.x] = acc;
    }
}

// ---------------------------------------------------------------------------
extern "C" void kernel_launch(void* const* d_in, const int* in_sizes, int n_in,
                              void* d_out, int out_size, void* d_ws, size_t ws_size,
                              hipStream_t stream)
{
    const float* x      = (const float*)d_in[0];
    const float* xdims  = (const float*)d_in[1];
    const int*   stt    = (const int*)d_in[2];
    const int*   eidx   = (const int*)d_in[3];
    const int*   batch  = (const int*)d_in[4];
    const float* st_emb = (const float*)d_in[5];
    const float* Wl1 = (const float*)d_in[6];
    const float* bl1 = (const float*)d_in[7];
    const float* Wr1 = (const float*)d_in[8];
    const float* g1  = (const float*)d_in[9];
    const float* be1 = (const float*)d_in[10];
    const float* Wl2 = (const float*)d_in[11];
    const float* bl2 = (const float*)d_in[12];
    const float* Wr2 = (const float*)d_in[13];
    const float* g2  = (const float*)d_in[14];
    const float* be2 = (const float*)d_in[15];
    const float* Wlin = (const float*)d_in[16];
    const float* blin = (const float*)d_in[17];
    float* out = (float*)d_out;

    const int* esrc_in = eidx;
    const int* edst_in = eidx + N_EDGES;

    char* ws = (char*)d_ws;
    size_t o = 0;
    auto carve = [&](size_t bytes) { void* p = ws + o; o = (o + bytes + 255) & ~(size_t)255; return p; };
    unsigned short* Xc1  = (unsigned short*)carve((size_t)N_NODES * 96 * 2);
    unsigned short* Xc2  = (unsigned short*)carve((size_t)N_NODES * 256 * 2);
    unsigned short* h2bf = (unsigned short*)carve((size_t)N_NODES * 128 * 2);
    unsigned short* Wc1  = (unsigned short*)carve((size_t)128 * 96 * 2);
    unsigned short* Wc2  = (unsigned short*)carve((size_t)128 * 256 * 2);
    int*   cnt    = (int*)carve((size_t)N_NODES * 4);
    int*   offs   = (int*)carve((size_t)(N_NODES + 1) * 4);
    int*   pos    = (int*)carve((size_t)N_NODES * 4);
    int*   esrc   = (int*)carve((size_t)N_EDGES * 4);
    int*   bsum   = (int*)carve((size_t)NB_SCAN * 4);
    int*   boffs  = (int*)carve((size_t)NB_SCAN * 4);
    float* pooled = (float*)carve((size_t)N_GRAPHS * 256 * 4);
    int*   starts = (int*)carve((size_t)(N_GRAPHS + 1) * 4);
    (void)ws_size;

    // weights -> bf16 concat
    wcat1_kernel<<<(128 * 96 + 255) / 256, 256, 0, stream>>>(Wl1, Wr1, Wc1);
    wcat2_kernel<<<(128 * 256 + 255) / 256, 256, 0, stream>>>(Wl2, Wr2, Wc2);

    // h0 -> Xcat1[:,0:48]
    h0_kernel<<<(N_NODES * 48 + 255) / 256, 256, 0, stream>>>(x, xdims, stt, st_emb, Xc1);

    // CSR by dst (hierarchical scan)
    hipMemsetAsync(cnt, 0, (size_t)N_NODES * 4, stream);
    count_kernel<<<(N_EDGES + 255) / 256, 256, 0, stream>>>(edst_in, cnt);
    scan_blocksum_kernel<<<NB_SCAN, 256, 0, stream>>>(cnt, bsum);
    scan_bsum_kernel<<<1, 256, 0, stream>>>(bsum, boffs, offs);
    scan_final_kernel<<<NB_SCAN, 256, 0, stream>>>(cnt, boffs, offs, pos);
    fill_kernel<<<(N_EDGES + 255) / 256, 256, 0, stream>>>(esrc_in, edst_in, pos, esrc);

    starts_kernel<<<(N_NODES + 255) / 256, 256, 0, stream>>>(batch, starts);

    // layer 1
    agg1_kernel<<<(N_NODES + 3) / 4, 256, 0, stream>>>(offs, esrc, Xc1);
    mfma_layer_kernel<96><<<(N_NODES + 127) / 128, 256, 0, stream>>>(
        Xc1, Wc1, bl1, g1, be1, Xc2, 256);

    // layer 2
    agg2_kernel<<<(N_NODES + 3) / 4, 256, 0, stream>>>(offs, esrc, Xc2);
    mfma_layer_kernel<256><<<(N_NODES + 127) / 128, 256, 0, stream>>>(
        Xc2, Wc2, bl2, g2, be2, h2bf, 128);

    // pooling + head
    pool_kernel<<<N_GRAPHS, 128, 0, stream>>>(h2bf, starts, pooled);
    head_kernel<<<N_GRAPHS, 256, 0, stream>>>(pooled, Wlin, blin, out);
}

// Round 5
// 169.942 us; speedup vs baseline: 3.3497x; 1.2343x over previous
//
#include <hip/hip_runtime.h>
#include <hip/hip_bf16.h>
#include <math.h>

#define N_NODES 50000
#define N_EDGES 600000
#define N_GRAPHS 512
#define LN_EPS 1e-5f
#define NB_SCAN ((N_NODES + 255) / 256)

typedef short bf16x8 __attribute__((ext_vector_type(8)));
typedef float f32x4 __attribute__((ext_vector_type(4)));

__device__ __forceinline__ unsigned short f2bf(float f) {
    unsigned int x = __float_as_uint(f);
    return (unsigned short)((x + 0x7fffu + ((x >> 16) & 1u)) >> 16);
}
__device__ __forceinline__ float bflo(unsigned int u) { return __uint_as_float(u << 16); }
__device__ __forceinline__ float bfhi(unsigned int u) { return __uint_as_float(u & 0xffff0000u); }

// ---------------------------------------------------------------------------
// fused prep: h0 -> Xc1 cols[0,48), Wcat1, Wcat2, cnt=0, starts
// grid covers N_NODES*48 elements (largest job)
__global__ __launch_bounds__(256) void prep_kernel(
    const float* __restrict__ x, const float* __restrict__ xdims,
    const int* __restrict__ stt, const float* __restrict__ st_emb,
    const float* __restrict__ Wl1, const float* __restrict__ Wr1,
    const float* __restrict__ Wl2, const float* __restrict__ Wr2,
    const int* __restrict__ batch,
    unsigned short* __restrict__ Xc1, unsigned short* __restrict__ Wc1,
    unsigned short* __restrict__ Wc2, int* __restrict__ cnt,
    int* __restrict__ starts)
{
    int idx = blockIdx.x * 256 + threadIdx.x;

    // job A: h0 build (cols 0..43 data, 44..47 zero), row stride 96
    if (idx < N_NODES * 48) {
        int n = idx / 48;
        int c = idx - n * 48;
        float v;
        if (c < 29)       v = x[n * 29 + c];
        else if (c < 32)  v = xdims[n * 3 + (c - 29)];
        else if (c < 44)  v = st_emb[stt[n] * 12 + (c - 32)];
        else              v = 0.f;
        Xc1[(size_t)n * 96 + c] = f2bf(v);
    }
    // job B: Wcat1 row f = [Wr1[f,:44] | 0x4 | Wl1[f,:44] | 0x4]
    if (idx < 128 * 96) {
        int f = idx / 96, k = idx - f * 96;
        float v;
        if (k < 44)       v = Wr1[f * 44 + k];
        else if (k < 48)  v = 0.f;
        else if (k < 92)  v = Wl1[f * 44 + (k - 48)];
        else              v = 0.f;
        Wc1[idx] = f2bf(v);
    }
    // job C: Wcat2 row f = [Wr2[f,:128] | Wl2[f,:128]]
    if (idx < 128 * 256) {
        int f = idx >> 8, k = idx & 255;
        float v = (k < 128) ? Wr2[f * 128 + k] : Wl2[f * 128 + (k - 128)];
        Wc2[idx] = f2bf(v);
    }
    // job D: zero degree counters + graph starts from sorted batch
    if (idx < N_NODES) {
        cnt[idx] = 0;
        int b = batch[idx];
        int pb = (idx == 0) ? -1 : batch[idx - 1];
        for (int g = pb + 1; g <= b; ++g) starts[g] = idx;
        if (idx == N_NODES - 1)
            for (int g = b + 1; g <= N_GRAPHS; ++g) starts[g] = N_NODES;
    }
}

// ---------------------------------------------------------------------------
// CSR build by dst
__global__ void count_kernel(const int* __restrict__ dst, int* __restrict__ cnt)
{
    int e = blockIdx.x * blockDim.x + threadIdx.x;
    if (e < N_EDGES) atomicAdd(&cnt[dst[e]], 1);
}

__global__ __launch_bounds__(256) void scan_blocksum_kernel(const int* __restrict__ cnt,
                                                            int* __restrict__ bsum)
{
    __shared__ int lds[4];
    int i = blockIdx.x * 256 + threadIdx.x;
    int v = (i < N_NODES) ? cnt[i] : 0;
    #pragma unroll
    for (int d = 32; d >= 1; d >>= 1) v += __shfl_down(v, d);
    int lane = threadIdx.x & 63, wv = threadIdx.x >> 6;
    if (lane == 0) lds[wv] = v;
    __syncthreads();
    if (threadIdx.x == 0) bsum[blockIdx.x] = lds[0] + lds[1] + lds[2] + lds[3];
}

__global__ __launch_bounds__(256) void scan_bsum_kernel(const int* __restrict__ bsum,
                                                        int* __restrict__ boffs,
                                                        int* __restrict__ offs)
{
    __shared__ int lds[4];
    int i = threadIdx.x;
    int v = (i < NB_SCAN) ? bsum[i] : 0;
    int lane = i & 63, wv = i >> 6;
    int incl = v;
    #pragma unroll
    for (int d = 1; d < 64; d <<= 1) {
        int t = __shfl_up(incl, d);
        if (lane >= d) incl += t;
    }
    if (lane == 63) lds[wv] = incl;
    __syncthreads();
    int add = 0;
    #pragma unroll
    for (int w = 0; w < 4; ++w) if (w < wv) add += lds[w];
    if (i < NB_SCAN) boffs[i] = add + incl - v;
    if (i == 0) offs[N_NODES] = N_EDGES;
}

__global__ __launch_bounds__(256) void scan_final_kernel(const int* __restrict__ cnt,
                                                         const int* __restrict__ boffs,
                                                         int* __restrict__ offs,
                                                         int* __restrict__ pos)
{
    __shared__ int lds[4];
    int i = blockIdx.x * 256 + threadIdx.x;
    int v = (i < N_NODES) ? cnt[i] : 0;
    int lane = threadIdx.x & 63, wv = threadIdx.x >> 6;
    int incl = v;
    #pragma unroll
    for (int d = 1; d < 64; d <<= 1) {
        int t = __shfl_up(incl, d);
        if (lane >= d) incl += t;
    }
    if (lane == 63) lds[wv] = incl;
    __syncthreads();
    int add = boffs[blockIdx.x];
    #pragma unroll
    for (int w = 0; w < 4; ++w) if (w < wv) add += lds[w];
    if (i < N_NODES) { int e = add + incl - v; offs[i] = e; pos[i] = e; }
}

__global__ void fill_kernel(const int* __restrict__ esrc_in, const int* __restrict__ edst_in,
                            int* __restrict__ pos, int* __restrict__ esrc_out)
{
    int e = blockIdx.x * blockDim.x + threadIdx.x;
    if (e < N_EDGES) {
        int p = atomicAdd(&pos[edst_in[e]], 1);
        esrc_out[p] = esrc_in[e];
    }
}

// ---------------------------------------------------------------------------
// agg1: wave per node; 8-lane groups each gather one edge; uint4 loads; 16-deep
__global__ __launch_bounds__(256) void agg1_kernel(const int* __restrict__ offs,
                                                   const int* __restrict__ esrc,
                                                   unsigned short* __restrict__ Xc)
{
    int n = blockIdx.x * 4 + (threadIdx.x >> 6);
    if (n >= N_NODES) return;
    const int lane = threadIdx.x & 63;
    const int grp = lane >> 3;      // 0..7 edge slot
    const int sl  = lane & 7;       // 0..7 col chunk (active < 6)
    const bool act = sl < 6;
    int s0 = offs[n], s1 = offs[n + 1];
    float a0=0.f,a1=0.f,a2=0.f,a3=0.f,a4=0.f,a5=0.f,a6=0.f,a7=0.f;
    const uint4* base = (const uint4*)Xc;
    int e = s0;
    for (; e + 16 <= s1; e += 16) {
        int srcA = esrc[e + grp];
        int srcB = esrc[e + 8 + grp];
        if (act) {
            uint4 va = base[(size_t)srcA * 12 + sl];
            uint4 vb = base[(size_t)srcB * 12 + sl];
            a0 += bflo(va.x); a1 += bfhi(va.x);
            a2 += bflo(va.y); a3 += bfhi(va.y);
            a4 += bflo(va.z); a5 += bfhi(va.z);
            a6 += bflo(va.w); a7 += bfhi(va.w);
            a0 += bflo(vb.x); a1 += bfhi(vb.x);
            a2 += bflo(vb.y); a3 += bfhi(vb.y);
            a4 += bflo(vb.z); a5 += bfhi(vb.z);
            a6 += bflo(vb.w); a7 += bfhi(vb.w);
        }
    }
    for (; e + 8 <= s1; e += 8) {
        int src = esrc[e + grp];
        if (act) {
            uint4 v = base[(size_t)src * 12 + sl];
            a0 += bflo(v.x); a1 += bfhi(v.x);
            a2 += bflo(v.y); a3 += bfhi(v.y);
            a4 += bflo(v.z); a5 += bfhi(v.z);
            a6 += bflo(v.w); a7 += bfhi(v.w);
        }
    }
    if (e + grp < s1) {
        int src = esrc[e + grp];
        if (act) {
            uint4 v = base[(size_t)src * 12 + sl];
            a0 += bflo(v.x); a1 += bfhi(v.x);
            a2 += bflo(v.y); a3 += bfhi(v.y);
            a4 += bflo(v.z); a5 += bfhi(v.z);
            a6 += bflo(v.w); a7 += bfhi(v.w);
        }
    }
    #pragma unroll
    for (int m = 8; m <= 32; m <<= 1) {
        a0 += __shfl_xor(a0, m); a1 += __shfl_xor(a1, m);
        a2 += __shfl_xor(a2, m); a3 += __shfl_xor(a3, m);
        a4 += __shfl_xor(a4, m); a5 += __shfl_xor(a5, m);
        a6 += __shfl_xor(a6, m); a7 += __shfl_xor(a7, m);
    }
    if (grp == 0 && act) {
        float inv = (s1 > s0) ? 1.f / (float)(s1 - s0) : 0.f;
        uint4 p;
        p.x = (unsigned int)f2bf(a0 * inv) | ((unsigned int)f2bf(a1 * inv) << 16);
        p.y = (unsigned int)f2bf(a2 * inv) | ((unsigned int)f2bf(a3 * inv) << 16);
        p.z = (unsigned int)f2bf(a4 * inv) | ((unsigned int)f2bf(a5 * inv) << 16);
        p.w = (unsigned int)f2bf(a6 * inv) | ((unsigned int)f2bf(a7 * inv) << 16);
        ((uint4*)Xc)[(size_t)n * 12 + 6 + sl] = p;
    }
}

// agg2: wave per node; 16-lane groups each gather one edge; uint4 loads; 16-deep
__global__ __launch_bounds__(256) void agg2_kernel(const int* __restrict__ offs,
                                                   const int* __restrict__ esrc,
                                                   unsigned short* __restrict__ Xc)
{
    int n = blockIdx.x * 4 + (threadIdx.x >> 6);
    if (n >= N_NODES) return;
    const int lane = threadIdx.x & 63;
    const int grp = lane >> 4;      // 0..3 edge slot
    const int sl  = lane & 15;      // 0..15 col chunk
    int s0 = offs[n], s1 = offs[n + 1];
    float a0=0.f,a1=0.f,a2=0.f,a3=0.f,a4=0.f,a5=0.f,a6=0.f,a7=0.f;
    const uint4* base = (const uint4*)Xc;
    int e = s0;
    for (; e + 16 <= s1; e += 16) {
        int srcA = esrc[e + grp];
        int srcB = esrc[e + 4 + grp];
        int srcC = esrc[e + 8 + grp];
        int srcD = esrc[e + 12 + grp];
        uint4 va = base[(size_t)srcA * 32 + sl];
        uint4 vb = base[(size_t)srcB * 32 + sl];
        uint4 vc = base[(size_t)srcC * 32 + sl];
        uint4 vd = base[(size_t)srcD * 32 + sl];
        a0 += bflo(va.x); a1 += bfhi(va.x);
        a2 += bflo(va.y); a3 += bfhi(va.y);
        a4 += bflo(va.z); a5 += bfhi(va.z);
        a6 += bflo(va.w); a7 += bfhi(va.w);
        a0 += bflo(vb.x); a1 += bfhi(vb.x);
        a2 += bflo(vb.y); a3 += bfhi(vb.y);
        a4 += bflo(vb.z); a5 += bfhi(vb.z);
        a6 += bflo(vb.w); a7 += bfhi(vb.w);
        a0 += bflo(vc.x); a1 += bfhi(vc.x);
        a2 += bflo(vc.y); a3 += bfhi(vc.y);
        a4 += bflo(vc.z); a5 += bfhi(vc.z);
        a6 += bflo(vc.w); a7 += bfhi(vc.w);
        a0 += bflo(vd.x); a1 += bfhi(vd.x);
        a2 += bflo(vd.y); a3 += bfhi(vd.y);
        a4 += bflo(vd.z); a5 += bfhi(vd.z);
        a6 += bflo(vd.w); a7 += bfhi(vd.w);
    }
    for (; e + 4 <= s1; e += 4) {
        int src = esrc[e + grp];
        uint4 v = base[(size_t)src * 32 + sl];
        a0 += bflo(v.x); a1 += bfhi(v.x);
        a2 += bflo(v.y); a3 += bfhi(v.y);
        a4 += bflo(v.z); a5 += bfhi(v.z);
        a6 += bflo(v.w); a7 += bfhi(v.w);
    }
    if (e + grp < s1) {
        int src = esrc[e + grp];
        uint4 v = base[(size_t)src * 32 + sl];
        a0 += bflo(v.x); a1 += bfhi(v.x);
        a2 += bflo(v.y); a3 += bfhi(v.y);
        a4 += bflo(v.z); a5 += bfhi(v.z);
        a6 += bflo(v.w); a7 += bfhi(v.w);
    }
    #pragma unroll
    for (int m = 16; m <= 32; m <<= 1) {
        a0 += __shfl_xor(a0, m); a1 += __shfl_xor(a1, m);
        a2 += __shfl_xor(a2, m); a3 += __shfl_xor(a3, m);
        a4 += __shfl_xor(a4, m); a5 += __shfl_xor(a5, m);
        a6 += __shfl_xor(a6, m); a7 += __shfl_xor(a7, m);
    }
    if (grp == 0) {
        float inv = (s1 > s0) ? 1.f / (float)(s1 - s0) : 0.f;
        uint4 p;
        p.x = (unsigned int)f2bf(a0 * inv) | ((unsigned int)f2bf(a1 * inv) << 16);
        p.y = (unsigned int)f2bf(a2 * inv) | ((unsigned int)f2bf(a3 * inv) << 16);
        p.z = (unsigned int)f2bf(a4 * inv) | ((unsigned int)f2bf(a5 * inv) << 16);
        p.w = (unsigned int)f2bf(a6 * inv) | ((unsigned int)f2bf(a7 * inv) << 16);
        ((uint4*)Xc)[(size_t)n * 32 + 16 + sl] = p;
    }
}

// ---------------------------------------------------------------------------
// fused MFMA layer: Out[node][f] = relu(LN(Xcat @ Wcat^T + bl)) as bf16
template <int KPAD>
__global__ __launch_bounds__(256) void mfma_layer_kernel(
    const unsigned short* __restrict__ X, const unsigned short* __restrict__ W,
    const float* __restrict__ bl, const float* __restrict__ g,
    const float* __restrict__ beta,
    unsigned short* __restrict__ Out, int outStride)
{
    const int lane = threadIdx.x & 63;
    const int wv   = threadIdx.x >> 6;
    const int l15  = lane & 15;
    const int l4   = lane >> 4;
    const int row0 = blockIdx.x * 128 + wv * 32;

    int rA0 = row0 + l15;       if (rA0 > N_NODES - 1) rA0 = N_NODES - 1;
    int rA1 = row0 + 16 + l15;  if (rA1 > N_NODES - 1) rA1 = N_NODES - 1;

    f32x4 acc[2][8];
    #pragma unroll
    for (int m = 0; m < 2; ++m)
        #pragma unroll
        for (int n = 0; n < 8; ++n) acc[m][n] = (f32x4){0.f, 0.f, 0.f, 0.f};

    const int kb = l4 * 8;
    #pragma unroll
    for (int ks = 0; ks < KPAD / 32; ++ks) {
        const int k = ks * 32 + kb;
        bf16x8 a0 = *(const bf16x8*)(X + (size_t)rA0 * KPAD + k);
        bf16x8 a1 = *(const bf16x8*)(X + (size_t)rA1 * KPAD + k);
        #pragma unroll
        for (int ni = 0; ni < 8; ++ni) {
            bf16x8 b = *(const bf16x8*)(W + (size_t)(ni * 16 + l15) * KPAD + k);
            acc[0][ni] = __builtin_amdgcn_mfma_f32_16x16x32_bf16(a0, b, acc[0][ni], 0, 0, 0);
            acc[1][ni] = __builtin_amdgcn_mfma_f32_16x16x32_bf16(a1, b, acc[1][ni], 0, 0, 0);
        }
    }

    float blv[8], gv[8], bev[8];
    #pragma unroll
    for (int ni = 0; ni < 8; ++ni) {
        int f = ni * 16 + l15;
        blv[ni] = bl[f]; gv[ni] = g[f]; bev[ni] = beta[f];
    }

    #pragma unroll
    for (int mi = 0; mi < 2; ++mi) {
        #pragma unroll
        for (int r = 0; r < 4; ++r) {
            float v[8];
            float s1 = 0.f, s2 = 0.f;
            #pragma unroll
            for (int ni = 0; ni < 8; ++ni) {
                float t = acc[mi][ni][r] + blv[ni];
                v[ni] = t; s1 += t; s2 += t * t;
            }
            #pragma unroll
            for (int m = 8; m >= 1; m >>= 1) {
                s1 += __shfl_xor(s1, m);
                s2 += __shfl_xor(s2, m);
            }
            float mu   = s1 * (1.f / 128.f);
            float var  = s2 * (1.f / 128.f) - mu * mu;
            float rstd = rsqrtf(var + LN_EPS);
            int node = row0 + mi * 16 + l4 * 4 + r;
            if (node < N_NODES) {
                #pragma unroll
                for (int ni = 0; ni < 8; ++ni) {
                    float o = gv[ni] * (v[ni] - mu) * rstd + bev[ni];
                    o = fmaxf(o, 0.f);
                    Out[(size_t)node * outStride + ni * 16 + l15] = f2bf(o);
                }
            }
        }
    }
}

// ---------------------------------------------------------------------------
// fused pooling (mean+max) + linear head. 1 block / graph, 256 threads.
// 64 col-pair lanes x 4 row-groups, 2-deep unroll = 8 rows in flight.
__global__ __launch_bounds__(256) void poolhead_kernel(const unsigned short* __restrict__ h2,
                                                       const int* __restrict__ starts,
                                                       const float* __restrict__ Wlin,
                                                       const float* __restrict__ blin,
                                                       float* __restrict__ out)
{
    const int g  = blockIdx.x;
    const int j2 = threadIdx.x & 63;   // col pair 2*j2, 2*j2+1
    const int h  = threadIdx.x >> 6;   // row group 0..3
    const int s0 = starts[g], s1 = starts[g + 1];
    float sa = 0.f, sb = 0.f, ma = -INFINITY, mb = -INFINITY;
    const unsigned int* base = (const unsigned int*)h2;   // row stride 64 uints
    int n = s0 + h;
    for (; n + 4 < s1; n += 8) {
        unsigned int u0 = base[(size_t)n * 64 + j2];
        unsigned int u1 = base[(size_t)(n + 4) * 64 + j2];
        float l0 = bflo(u0), h0 = bfhi(u0);
        float l1 = bflo(u1), h1 = bfhi(u1);
        sa += l0 + l1; sb += h0 + h1;
        ma = fmaxf(ma, fmaxf(l0, l1));
        mb = fmaxf(mb, fmaxf(h0, h1));
    }
    if (n < s1) {
        unsigned int u = base[(size_t)n * 64 + j2];
        float lo = bflo(u), hi = bfhi(u);
        sa += lo; sb += hi;
        ma = fmaxf(ma, lo); mb = fmaxf(mb, hi);
    }
    __shared__ float red[4][4][64];
    __shared__ float pooled[256];
    red[h][0][j2] = sa; red[h][1][j2] = sb; red[h][2][j2] = ma; red[h][3][j2] = mb;
    __syncthreads();
    if (h == 0) {
        #pragma unroll
        for (int o = 1; o < 4; ++o) {
            sa += red[o][0][j2]; sb += red[o][1][j2];
            ma = fmaxf(ma, red[o][2][j2]); mb = fmaxf(mb, red[o][3][j2]);
        }
        int c = s1 - s0;
        float inv = (c > 0) ? 1.f / (float)c : 0.f;
        pooled[2 * j2]           = sa * inv;
        pooled[2 * j2 + 1]       = sb * inv;
        pooled[128 + 2 * j2]     = (c > 0) ? ma : 0.f;
        pooled[128 + 2 * j2 + 1] = (c > 0) ? mb : 0.f;
    }
    __syncthreads();
    if (threadIdx.x < 10) {
        const float* w = Wlin + threadIdx.x * 256;
        float acc = blin[threadIdx.x];
        for (int k = 0; k < 256; ++k) acc += pooled[k] * w[k];
        out[g * 10 + threadIdx.x] = acc;
    }
}

// ---------------------------------------------------------------------------
extern "C" void kernel_launch(void* const* d_in, const int* in_sizes, int n_in,
                              void* d_out, int out_size, void* d_ws, size_t ws_size,
                              hipStream_t stream)
{
    const float* x      = (const float*)d_in[0];
    const float* xdims  = (const float*)d_in[1];
    const int*   stt    = (const int*)d_in[2];
    const int*   eidx   = (const int*)d_in[3];
    const int*   batch  = (const int*)d_in[4];
    const float* st_emb = (const float*)d_in[5];
    const float* Wl1 = (const float*)d_in[6];
    const float* bl1 = (const float*)d_in[7];
    const float* Wr1 = (const float*)d_in[8];
    const float* g1  = (const float*)d_in[9];
    const float* be1 = (const float*)d_in[10];
    const float* Wl2 = (const float*)d_in[11];
    const float* bl2 = (const float*)d_in[12];
    const float* Wr2 = (const float*)d_in[13];
    const float* g2  = (const float*)d_in[14];
    const float* be2 = (const float*)d_in[15];
    const float* Wlin = (const float*)d_in[16];
    const float* blin = (const float*)d_in[17];
    float* out = (float*)d_out;

    const int* esrc_in = eidx;
    const int* edst_in = eidx + N_EDGES;

    char* ws = (char*)d_ws;
    size_t o = 0;
    auto carve = [&](size_t bytes) { void* p = ws + o; o = (o + bytes + 255) & ~(size_t)255; return p; };
    unsigned short* Xc1  = (unsigned short*)carve((size_t)N_NODES * 96 * 2);
    unsigned short* Xc2  = (unsigned short*)carve((size_t)N_NODES * 256 * 2);
    unsigned short* h2bf = (unsigned short*)carve((size_t)N_NODES * 128 * 2);
    unsigned short* Wc1  = (unsigned short*)carve((size_t)128 * 96 * 2);
    unsigned short* Wc2  = (unsigned short*)carve((size_t)128 * 256 * 2);
    int*   cnt    = (int*)carve((size_t)N_NODES * 4);
    int*   offs   = (int*)carve((size_t)(N_NODES + 1) * 4);
    int*   pos    = (int*)carve((size_t)N_NODES * 4);
    int*   esrc   = (int*)carve((size_t)N_EDGES * 4);
    int*   bsum   = (int*)carve((size_t)NB_SCAN * 4);
    int*   boffs  = (int*)carve((size_t)NB_SCAN * 4);
    int*   starts = (int*)carve((size_t)(N_GRAPHS + 1) * 4);
    (void)ws_size;

    // fused prep: h0, weight concat, cnt zero, graph starts
    prep_kernel<<<(N_NODES * 48 + 255) / 256, 256, 0, stream>>>(
        x, xdims, stt, st_emb, Wl1, Wr1, Wl2, Wr2, batch,
        Xc1, Wc1, Wc2, cnt, starts);

    // CSR by dst (hierarchical scan)
    count_kernel<<<(N_EDGES + 255) / 256, 256, 0, stream>>>(edst_in, cnt);
    scan_blocksum_kernel<<<NB_SCAN, 256, 0, stream>>>(cnt, bsum);
    scan_bsum_kernel<<<1, 256, 0, stream>>>(bsum, boffs, offs);
    scan_final_kernel<<<NB_SCAN, 256, 0, stream>>>(cnt, boffs, offs, pos);
    fill_kernel<<<(N_EDGES + 255) / 256, 256, 0, stream>>>(esrc_in, edst_in, pos, esrc);

    // layer 1
    agg1_kernel<<<(N_NODES + 3) / 4, 256, 0, stream>>>(offs, esrc, Xc1);
    mfma_layer_kernel<96><<<(N_NODES + 127) / 128, 256, 0, stream>>>(
        Xc1, Wc1, bl1, g1, be1, Xc2, 256);

    // layer 2
    agg2_kernel<<<(N_NODES + 3) / 4, 256, 0, stream>>>(offs, esrc, Xc2);
    mfma_layer_kernel<256><<<(N_NODES + 127) / 128, 256, 0, stream>>>(
        Xc2, Wc2, bl2, g2, be2, h2bf, 128);

    // fused pooling + head
    poolhead_kernel<<<N_GRAPHS, 256, 0, stream>>>(h2bf, starts, Wlin, blin, out);
}

// Round 6
// 134.599 us; speedup vs baseline: 4.2292x; 1.2626x over previous
//
#include <hip/hip_runtime.h>
#include <hip/hip_bf16.h>
#include <math.h>

#define N_NODES 50000
#define N_EDGES 600000
#define N_GRAPHS 512
#define LN_EPS 1e-5f
#define CAP 96
#define EDGE_BLOCKS ((N_EDGES + 255) / 256)
#define PREP_BLOCKS ((N_NODES * 48 + 255) / 256)

typedef short bf16x8 __attribute__((ext_vector_type(8)));
typedef float f32x4 __attribute__((ext_vector_type(4)));

__device__ __forceinline__ unsigned short f2bf(float f) {
    unsigned int x = __float_as_uint(f);
    return (unsigned short)((x + 0x7fffu + ((x >> 16) & 1u)) >> 16);
}
__device__ __forceinline__ float bflo(unsigned int u) { return __uint_as_float(u << 16); }
__device__ __forceinline__ float bfhi(unsigned int u) { return __uint_as_float(u & 0xffff0000u); }

// ---------------------------------------------------------------------------
__global__ __launch_bounds__(256) void zero_kernel(int* __restrict__ cnt)
{
    int i = blockIdx.x * 256 + threadIdx.x;
    if (i < N_NODES) cnt[i] = 0;
}

// ---------------------------------------------------------------------------
// fused: edge->padded-adjacency fill  +  h0 build  +  weight concat  +  starts
// blocks [0, EDGE_BLOCKS) do the edge pass; the rest do prep jobs.
__global__ __launch_bounds__(256) void prep_fill_kernel(
    const float* __restrict__ x, const float* __restrict__ xdims,
    const int* __restrict__ stt, const float* __restrict__ st_emb,
    const float* __restrict__ Wl1, const float* __restrict__ Wr1,
    const float* __restrict__ Wl2, const float* __restrict__ Wr2,
    const int* __restrict__ batch,
    const int* __restrict__ esrc_in, const int* __restrict__ edst_in,
    unsigned short* __restrict__ Xc1, unsigned short* __restrict__ Wc1,
    unsigned short* __restrict__ Wc2, int* __restrict__ cnt,
    int* __restrict__ esrc_pad, int* __restrict__ starts)
{
    if (blockIdx.x < EDGE_BLOCKS) {
        int e = blockIdx.x * 256 + threadIdx.x;
        if (e < N_EDGES) {
            int d = edst_in[e];
            int slot = atomicAdd(&cnt[d], 1);
            if (slot < CAP) esrc_pad[(size_t)d * CAP + slot] = esrc_in[e];
        }
        return;
    }
    int idx = (blockIdx.x - EDGE_BLOCKS) * 256 + threadIdx.x;

    // job A: h0 build (cols 0..43 data, 44..47 zero), row stride 96
    if (idx < N_NODES * 48) {
        int n = idx / 48;
        int c = idx - n * 48;
        float v;
        if (c < 29)       v = x[n * 29 + c];
        else if (c < 32)  v = xdims[n * 3 + (c - 29)];
        else if (c < 44)  v = st_emb[stt[n] * 12 + (c - 32)];
        else              v = 0.f;
        Xc1[(size_t)n * 96 + c] = f2bf(v);
    }
    // job B: Wcat1 row f = [Wr1[f,:44] | 0x4 | Wl1[f,:44] | 0x4]
    if (idx < 128 * 96) {
        int f = idx / 96, k = idx - f * 96;
        float v;
        if (k < 44)       v = Wr1[f * 44 + k];
        else if (k < 48)  v = 0.f;
        else if (k < 92)  v = Wl1[f * 44 + (k - 48)];
        else              v = 0.f;
        Wc1[idx] = f2bf(v);
    }
    // job C: Wcat2 row f = [Wr2[f,:128] | Wl2[f,:128]]
    if (idx < 128 * 256) {
        int f = idx >> 8, k = idx & 255;
        float v = (k < 128) ? Wr2[f * 128 + k] : Wl2[f * 128 + (k - 128)];
        Wc2[idx] = f2bf(v);
    }
    // job D: graph starts from sorted batch
    if (idx < N_NODES) {
        int b = batch[idx];
        int pb = (idx == 0) ? -1 : batch[idx - 1];
        for (int g = pb + 1; g <= b; ++g) starts[g] = idx;
        if (idx == N_NODES - 1)
            for (int g = b + 1; g <= N_GRAPHS; ++g) starts[g] = N_NODES;
    }
}

// ---------------------------------------------------------------------------
// agg1: wave per node. 8-lane groups x 2 clamped loads -> 16 edges/iter.
// Edge indices 0..63 preloaded 1/lane, fetched via shfl (no index-load hop).
// Row = 12 uint4 (96 cols); gather chunks 0..5 (cols 0..47), write 6..11.
__global__ __launch_bounds__(256) void agg1_kernel(const int* __restrict__ cnt,
                                                   const int* __restrict__ esrc_pad,
                                                   unsigned short* __restrict__ Xc)
{
    int n = blockIdx.x * 4 + (threadIdx.x >> 6);
    if (n >= N_NODES) return;
    const int lane = threadIdx.x & 63;
    const int grp = lane >> 3;          // 0..7 edge slot
    const int sl  = lane & 7;           // 0..7 col chunk
    const int slc = (sl < 5) ? sl : 5;  // clamp: lanes 6,7 duplicate chunk 5
    int degT = cnt[n];
    int deg  = (degT < CAP) ? degT : CAP;
    int er = esrc_pad[(size_t)n * CAP + lane];   // edges 0..63
    float a0=0.f,a1=0.f,a2=0.f,a3=0.f,a4=0.f,a5=0.f,a6=0.f,a7=0.f;
    const uint4* base = (const uint4*)Xc;
    const int c1 = deg - 1;
    int lim = (deg < 64) ? deg : 64;
    for (int e = 0; e < lim; e += 16) {
        int eA = e + grp, eB = eA + 8;
        int sA = __shfl(er, (eA < c1) ? eA : c1);
        int sB = __shfl(er, (eB < c1) ? eB : c1);
        uint4 va = base[(size_t)sA * 12 + slc];
        uint4 vb = base[(size_t)sB * 12 + slc];
        float mA = (eA < deg) ? 1.f : 0.f;
        float mB = (eB < deg) ? 1.f : 0.f;
        a0 += mA * bflo(va.x) + mB * bflo(vb.x);
        a1 += mA * bfhi(va.x) + mB * bfhi(vb.x);
        a2 += mA * bflo(va.y) + mB * bflo(vb.y);
        a3 += mA * bfhi(va.y) + mB * bfhi(vb.y);
        a4 += mA * bflo(va.z) + mB * bflo(vb.z);
        a5 += mA * bfhi(va.z) + mB * bfhi(vb.z);
        a6 += mA * bflo(va.w) + mB * bflo(vb.w);
        a7 += mA * bfhi(va.w) + mB * bfhi(vb.w);
    }
    for (int e = 64; e < deg; e += 16) {       // deg>64: ~never
        int eA = e + grp, eB = eA + 8;
        int sA = esrc_pad[(size_t)n * CAP + ((eA < c1) ? eA : c1)];
        int sB = esrc_pad[(size_t)n * CAP + ((eB < c1) ? eB : c1)];
        uint4 va = base[(size_t)sA * 12 + slc];
        uint4 vb = base[(size_t)sB * 12 + slc];
        float mA = (eA < deg) ? 1.f : 0.f;
        float mB = (eB < deg) ? 1.f : 0.f;
        a0 += mA * bflo(va.x) + mB * bflo(vb.x);
        a1 += mA * bfhi(va.x) + mB * bfhi(vb.x);
        a2 += mA * bflo(va.y) + mB * bflo(vb.y);
        a3 += mA * bfhi(va.y) + mB * bfhi(vb.y);
        a4 += mA * bflo(va.z) + mB * bflo(vb.z);
        a5 += mA * bfhi(va.z) + mB * bfhi(vb.z);
        a6 += mA * bflo(va.w) + mB * bflo(vb.w);
        a7 += mA * bfhi(va.w) + mB * bfhi(vb.w);
    }
    #pragma unroll
    for (int m = 8; m <= 32; m <<= 1) {
        a0 += __shfl_xor(a0, m); a1 += __shfl_xor(a1, m);
        a2 += __shfl_xor(a2, m); a3 += __shfl_xor(a3, m);
        a4 += __shfl_xor(a4, m); a5 += __shfl_xor(a5, m);
        a6 += __shfl_xor(a6, m); a7 += __shfl_xor(a7, m);
    }
    if (grp == 0 && sl < 6) {
        float inv = (degT > 0) ? 1.f / (float)degT : 0.f;
        uint4 p;
        p.x = (unsigned int)f2bf(a0 * inv) | ((unsigned int)f2bf(a1 * inv) << 16);
        p.y = (unsigned int)f2bf(a2 * inv) | ((unsigned int)f2bf(a3 * inv) << 16);
        p.z = (unsigned int)f2bf(a4 * inv) | ((unsigned int)f2bf(a5 * inv) << 16);
        p.w = (unsigned int)f2bf(a6 * inv) | ((unsigned int)f2bf(a7 * inv) << 16);
        ((uint4*)Xc)[(size_t)n * 12 + 6 + sl] = p;
    }
}

// agg2: wave per node. 16-lane groups x 4 clamped loads -> 16 edges/iter.
// Row = 32 uint4 (256 cols); gather chunks 0..15, write 16..31.
__global__ __launch_bounds__(256) void agg2_kernel(const int* __restrict__ cnt,
                                                   const int* __restrict__ esrc_pad,
                                                   unsigned short* __restrict__ Xc)
{
    int n = blockIdx.x * 4 + (threadIdx.x >> 6);
    if (n >= N_NODES) return;
    const int lane = threadIdx.x & 63;
    const int grp = lane >> 4;      // 0..3 edge slot
    const int sl  = lane & 15;      // col chunk
    int degT = cnt[n];
    int deg  = (degT < CAP) ? degT : CAP;
    int er = esrc_pad[(size_t)n * CAP + lane];
    float a0=0.f,a1=0.f,a2=0.f,a3=0.f,a4=0.f,a5=0.f,a6=0.f,a7=0.f;
    const uint4* base = (const uint4*)Xc;
    const int c1 = deg - 1;
    int lim = (deg < 64) ? deg : 64;
    for (int e = 0; e < lim; e += 16) {
        int eA = e + grp, eB = eA + 4, eC = eA + 8, eD = eA + 12;
        int sA = __shfl(er, (eA < c1) ? eA : c1);
        int sB = __shfl(er, (eB < c1) ? eB : c1);
        int sC = __shfl(er, (eC < c1) ? eC : c1);
        int sD = __shfl(er, (eD < c1) ? eD : c1);
        uint4 va = base[(size_t)sA * 32 + sl];
        uint4 vb = base[(size_t)sB * 32 + sl];
        uint4 vc = base[(size_t)sC * 32 + sl];
        uint4 vd = base[(size_t)sD * 32 + sl];
        float mA = (eA < deg) ? 1.f : 0.f;
        float mB = (eB < deg) ? 1.f : 0.f;
        float mC = (eC < deg) ? 1.f : 0.f;
        float mD = (eD < deg) ? 1.f : 0.f;
        a0 += mA * bflo(va.x) + mB * bflo(vb.x) + mC * bflo(vc.x) + mD * bflo(vd.x);
        a1 += mA * bfhi(va.x) + mB * bfhi(vb.x) + mC * bfhi(vc.x) + mD * bfhi(vd.x);
        a2 += mA * bflo(va.y) + mB * bflo(vb.y) + mC * bflo(vc.y) + mD * bflo(vd.y);
        a3 += mA * bfhi(va.y) + mB * bfhi(vb.y) + mC * bfhi(vc.y) + mD * bfhi(vd.y);
        a4 += mA * bflo(va.z) + mB * bflo(vb.z) + mC * bflo(vc.z) + mD * bflo(vd.z);
        a5 += mA * bfhi(va.z) + mB * bfhi(vb.z) + mC * bfhi(vc.z) + mD * bfhi(vd.z);
        a6 += mA * bflo(va.w) + mB * bflo(vb.w) + mC * bflo(vc.w) + mD * bflo(vd.w);
        a7 += mA * bfhi(va.w) + mB * bfhi(vb.w) + mC * bfhi(vc.w) + mD * bfhi(vd.w);
    }
    for (int e = 64; e < deg; e += 16) {       // deg>64: ~never
        int eA = e + grp, eB = eA + 4, eC = eA + 8, eD = eA + 12;
        int sA = esrc_pad[(size_t)n * CAP + ((eA < c1) ? eA : c1)];
        int sB = esrc_pad[(size_t)n * CAP + ((eB < c1) ? eB : c1)];
        int sC = esrc_pad[(size_t)n * CAP + ((eC < c1) ? eC : c1)];
        int sD = esrc_pad[(size_t)n * CAP + ((eD < c1) ? eD : c1)];
        uint4 va = base[(size_t)sA * 32 + sl];
        uint4 vb = base[(size_t)sB * 32 + sl];
        uint4 vc = base[(size_t)sC * 32 + sl];
        uint4 vd = base[(size_t)sD * 32 + sl];
        float mA = (eA < deg) ? 1.f : 0.f;
        float mB = (eB < deg) ? 1.f : 0.f;
        float mC = (eC < deg) ? 1.f : 0.f;
        float mD = (eD < deg) ? 1.f : 0.f;
        a0 += mA * bflo(va.x) + mB * bflo(vb.x) + mC * bflo(vc.x) + mD * bflo(vd.x);
        a1 += mA * bfhi(va.x) + mB * bfhi(vb.x) + mC * bfhi(vc.x) + mD * bfhi(vd.x);
        a2 += mA * bflo(va.y) + mB * bflo(vb.y) + mC * bflo(vc.y) + mD * bflo(vd.y);
        a3 += mA * bfhi(va.y) + mB * bfhi(vb.y) + mC * bfhi(vc.y) + mD * bfhi(vd.y);
        a4 += mA * bflo(va.z) + mB * bflo(vb.z) + mC * bflo(vc.z) + mD * bflo(vd.z);
        a5 += mA * bfhi(va.z) + mB * bfhi(vb.z) + mC * bfhi(vc.z) + mD * bfhi(vd.z);
        a6 += mA * bflo(va.w) + mB * bflo(vb.w) + mC * bflo(vc.w) + mD * bflo(vd.w);
        a7 += mA * bfhi(va.w) + mB * bfhi(vb.w) + mC * bfhi(vc.w) + mD * bfhi(vd.w);
    }
    #pragma unroll
    for (int m = 16; m <= 32; m <<= 1) {
        a0 += __shfl_xor(a0, m); a1 += __shfl_xor(a1, m);
        a2 += __shfl_xor(a2, m); a3 += __shfl_xor(a3, m);
        a4 += __shfl_xor(a4, m); a5 += __shfl_xor(a5, m);
        a6 += __shfl_xor(a6, m); a7 += __shfl_xor(a7, m);
    }
    if (grp == 0) {
        float inv = (degT > 0) ? 1.f / (float)degT : 0.f;
        uint4 p;
        p.x = (unsigned int)f2bf(a0 * inv) | ((unsigned int)f2bf(a1 * inv) << 16);
        p.y = (unsigned int)f2bf(a2 * inv) | ((unsigned int)f2bf(a3 * inv) << 16);
        p.z = (unsigned int)f2bf(a4 * inv) | ((unsigned int)f2bf(a5 * inv) << 16);
        p.w = (unsigned int)f2bf(a6 * inv) | ((unsigned int)f2bf(a7 * inv) << 16);
        ((uint4*)Xc)[(size_t)n * 32 + 16 + sl] = p;
    }
}

// ---------------------------------------------------------------------------
// fused MFMA layer: Out[node][f] = relu(LN(Xcat @ Wcat^T + bl)) as bf16
template <int KPAD>
__global__ __launch_bounds__(256) void mfma_layer_kernel(
    const unsigned short* __restrict__ X, const unsigned short* __restrict__ W,
    const float* __restrict__ bl, const float* __restrict__ g,
    const float* __restrict__ beta,
    unsigned short* __restrict__ Out, int outStride)
{
    const int lane = threadIdx.x & 63;
    const int wv   = threadIdx.x >> 6;
    const int l15  = lane & 15;
    const int l4   = lane >> 4;
    const int row0 = blockIdx.x * 128 + wv * 32;

    int rA0 = row0 + l15;       if (rA0 > N_NODES - 1) rA0 = N_NODES - 1;
    int rA1 = row0 + 16 + l15;  if (rA1 > N_NODES - 1) rA1 = N_NODES - 1;

    f32x4 acc[2][8];
    #pragma unroll
    for (int m = 0; m < 2; ++m)
        #pragma unroll
        for (int n = 0; n < 8; ++n) acc[m][n] = (f32x4){0.f, 0.f, 0.f, 0.f};

    const int kb = l4 * 8;
    #pragma unroll
    for (int ks = 0; ks < KPAD / 32; ++ks) {
        const int k = ks * 32 + kb;
        bf16x8 a0 = *(const bf16x8*)(X + (size_t)rA0 * KPAD + k);
        bf16x8 a1 = *(const bf16x8*)(X + (size_t)rA1 * KPAD + k);
        #pragma unroll
        for (int ni = 0; ni < 8; ++ni) {
            bf16x8 b = *(const bf16x8*)(W + (size_t)(ni * 16 + l15) * KPAD + k);
            acc[0][ni] = __builtin_amdgcn_mfma_f32_16x16x32_bf16(a0, b, acc[0][ni], 0, 0, 0);
            acc[1][ni] = __builtin_amdgcn_mfma_f32_16x16x32_bf16(a1, b, acc[1][ni], 0, 0, 0);
        }
    }

    float blv[8], gv[8], bev[8];
    #pragma unroll
    for (int ni = 0; ni < 8; ++ni) {
        int f = ni * 16 + l15;
        blv[ni] = bl[f]; gv[ni] = g[f]; bev[ni] = beta[f];
    }

    #pragma unroll
    for (int mi = 0; mi < 2; ++mi) {
        #pragma unroll
        for (int r = 0; r < 4; ++r) {
            float v[8];
            float s1 = 0.f, s2 = 0.f;
            #pragma unroll
            for (int ni = 0; ni < 8; ++ni) {
                float t = acc[mi][ni][r] + blv[ni];
                v[ni] = t; s1 += t; s2 += t * t;
            }
            #pragma unroll
            for (int m = 8; m >= 1; m >>= 1) {
                s1 += __shfl_xor(s1, m);
                s2 += __shfl_xor(s2, m);
            }
            float mu   = s1 * (1.f / 128.f);
            float var  = s2 * (1.f / 128.f) - mu * mu;
            float rstd = rsqrtf(var + LN_EPS);
            int node = row0 + mi * 16 + l4 * 4 + r;
            if (node < N_NODES) {
                #pragma unroll
                for (int ni = 0; ni < 8; ++ni) {
                    float o = gv[ni] * (v[ni] - mu) * rstd + bev[ni];
                    o = fmaxf(o, 0.f);
                    Out[(size_t)node * outStride + ni * 16 + l15] = f2bf(o);
                }
            }
        }
    }
}

// ---------------------------------------------------------------------------
// fused pooling (mean+max) + linear head. 1 block / graph, 256 threads.
__global__ __launch_bounds__(256) void poolhead_kernel(const unsigned short* __restrict__ h2,
                                                       const int* __restrict__ starts,
                                                       const float* __restrict__ Wlin,
                                                       const float* __restrict__ blin,
                                                       float* __restrict__ out)
{
    const int g  = blockIdx.x;
    const int j2 = threadIdx.x & 63;   // col pair 2*j2, 2*j2+1
    const int h  = threadIdx.x >> 6;   // row group 0..3
    const int s0 = starts[g], s1 = starts[g + 1];
    float sa = 0.f, sb = 0.f, ma = -INFINITY, mb = -INFINITY;
    const unsigned int* base = (const unsigned int*)h2;   // row stride 64 uints
    int n = s0 + h;
    for (; n + 4 < s1; n += 8) {
        unsigned int u0 = base[(size_t)n * 64 + j2];
        unsigned int u1 = base[(size_t)(n + 4) * 64 + j2];
        float l0 = bflo(u0), h0 = bfhi(u0);
        float l1 = bflo(u1), h1 = bfhi(u1);
        sa += l0 + l1; sb += h0 + h1;
        ma = fmaxf(ma, fmaxf(l0, l1));
        mb = fmaxf(mb, fmaxf(h0, h1));
    }
    if (n < s1) {
        unsigned int u = base[(size_t)n * 64 + j2];
        float lo = bflo(u), hi = bfhi(u);
        sa += lo; sb += hi;
        ma = fmaxf(ma, lo); mb = fmaxf(mb, hi);
    }
    __shared__ float red[4][4][64];
    __shared__ float pooled[256];
    red[h][0][j2] = sa; red[h][1][j2] = sb; red[h][2][j2] = ma; red[h][3][j2] = mb;
    __syncthreads();
    if (h == 0) {
        #pragma unroll
        for (int o = 1; o < 4; ++o) {
            sa += red[o][0][j2]; sb += red[o][1][j2];
            ma = fmaxf(ma, red[o][2][j2]); mb = fmaxf(mb, red[o][3][j2]);
        }
        int c = s1 - s0;
        float inv = (c > 0) ? 1.f / (float)c : 0.f;
        pooled[2 * j2]           = sa * inv;
        pooled[2 * j2 + 1]       = sb * inv;
        pooled[128 + 2 * j2]     = (c > 0) ? ma : 0.f;
        pooled[128 + 2 * j2 + 1] = (c > 0) ? mb : 0.f;
    }
    __syncthreads();
    if (threadIdx.x < 10) {
        const float* w = Wlin + threadIdx.x * 256;
        float acc = blin[threadIdx.x];
        for (int k = 0; k < 256; ++k) acc += pooled[k] * w[k];
        out[g * 10 + threadIdx.x] = acc;
    }
}

// ---------------------------------------------------------------------------
extern "C" void kernel_launch(void* const* d_in, const int* in_sizes, int n_in,
                              void* d_out, int out_size, void* d_ws, size_t ws_size,
                              hipStream_t stream)
{
    const float* x      = (const float*)d_in[0];
    const float* xdims  = (const float*)d_in[1];
    const int*   stt    = (const int*)d_in[2];
    const int*   eidx   = (const int*)d_in[3];
    const int*   batch  = (const int*)d_in[4];
    const float* st_emb = (const float*)d_in[5];
    const float* Wl1 = (const float*)d_in[6];
    const float* bl1 = (const float*)d_in[7];
    const float* Wr1 = (const float*)d_in[8];
    const float* g1  = (const float*)d_in[9];
    const float* be1 = (const float*)d_in[10];
    const float* Wl2 = (const float*)d_in[11];
    const float* bl2 = (const float*)d_in[12];
    const float* Wr2 = (const float*)d_in[13];
    const float* g2  = (const float*)d_in[14];
    const float* be2 = (const float*)d_in[15];
    const float* Wlin = (const float*)d_in[16];
    const float* blin = (const float*)d_in[17];
    float* out = (float*)d_out;

    const int* esrc_in = eidx;
    const int* edst_in = eidx + N_EDGES;

    char* ws = (char*)d_ws;
    size_t o = 0;
    auto carve = [&](size_t bytes) { void* p = ws + o; o = (o + bytes + 255) & ~(size_t)255; return p; };
    unsigned short* Xc1  = (unsigned short*)carve((size_t)N_NODES * 96 * 2);
    unsigned short* Xc2  = (unsigned short*)carve((size_t)N_NODES * 256 * 2);
    unsigned short* h2bf = (unsigned short*)carve((size_t)N_NODES * 128 * 2);
    unsigned short* Wc1  = (unsigned short*)carve((size_t)128 * 96 * 2);
    unsigned short* Wc2  = (unsigned short*)carve((size_t)128 * 256 * 2);
    int*   cnt      = (int*)carve((size_t)N_NODES * 4);
    int*   esrc_pad = (int*)carve((size_t)N_NODES * CAP * 4);
    int*   starts   = (int*)carve((size_t)(N_GRAPHS + 1) * 4);
    (void)ws_size;

    // 1. zero degree counters (tiny)
    zero_kernel<<<(N_NODES + 255) / 256, 256, 0, stream>>>(cnt);

    // 2. fused edge fill + h0 + weight concat + graph starts
    prep_fill_kernel<<<EDGE_BLOCKS + PREP_BLOCKS, 256, 0, stream>>>(
        x, xdims, stt, st_emb, Wl1, Wr1, Wl2, Wr2, batch,
        esrc_in, edst_in, Xc1, Wc1, Wc2, cnt, esrc_pad, starts);

    // 3-4. layer 1
    agg1_kernel<<<(N_NODES + 3) / 4, 256, 0, stream>>>(cnt, esrc_pad, Xc1);
    mfma_layer_kernel<96><<<(N_NODES + 127) / 128, 256, 0, stream>>>(
        Xc1, Wc1, bl1, g1, be1, Xc2, 256);

    // 5-6. layer 2
    agg2_kernel<<<(N_NODES + 3) / 4, 256, 0, stream>>>(cnt, esrc_pad, Xc2);
    mfma_layer_kernel<256><<<(N_NODES + 127) / 128, 256, 0, stream>>>(
        Xc2, Wc2, bl2, g2, be2, h2bf, 128);

    // 7. fused pooling + head
    poolhead_kernel<<<N_GRAPHS, 256, 0, stream>>>(h2bf, starts, Wlin, blin, out);
}

// Round 7
// 130.775 us; speedup vs baseline: 4.3529x; 1.0292x over previous
//
#include <hip/hip_runtime.h>
#include <hip/hip_bf16.h>
#include <math.h>

#define N_NODES 50000
#define N_EDGES 600000
#define N_GRAPHS 512
#define LN_EPS 1e-5f
#define CAP 96
#define EDGE_BLOCKS ((N_EDGES / 4 + 255) / 256)
#define PREP_BLOCKS ((N_NODES * 48 + 255) / 256)

typedef short bf16x8 __attribute__((ext_vector_type(8)));
typedef float f32x4 __attribute__((ext_vector_type(4)));

__device__ __forceinline__ unsigned short f2bf(float f) {
    unsigned int x = __float_as_uint(f);
    return (unsigned short)((x + 0x7fffu + ((x >> 16) & 1u)) >> 16);
}
__device__ __forceinline__ float bflo(unsigned int u) { return __uint_as_float(u << 16); }
__device__ __forceinline__ float bfhi(unsigned int u) { return __uint_as_float(u & 0xffff0000u); }

// ---------------------------------------------------------------------------
__global__ __launch_bounds__(256) void zero_kernel(int* __restrict__ cnt)
{
    int i = blockIdx.x * 256 + threadIdx.x;
    if (i < N_NODES) cnt[i] = 0;
}

// ---------------------------------------------------------------------------
// fused: edge->padded-adjacency fill (4 edges/thread, int4 loads, 4 indep
// atomic chains)  +  h0 build  +  weight concat  +  starts
__global__ __launch_bounds__(256) void prep_fill_kernel(
    const float* __restrict__ x, const float* __restrict__ xdims,
    const int* __restrict__ stt, const float* __restrict__ st_emb,
    const float* __restrict__ Wl1, const float* __restrict__ Wr1,
    const float* __restrict__ Wl2, const float* __restrict__ Wr2,
    const int* __restrict__ batch,
    const int* __restrict__ esrc_in, const int* __restrict__ edst_in,
    unsigned short* __restrict__ Xc1, unsigned short* __restrict__ Wc1,
    unsigned short* __restrict__ Wc2, int* __restrict__ cnt,
    int* __restrict__ esrc_pad, int* __restrict__ starts)
{
    if (blockIdx.x < EDGE_BLOCKS) {
        int t = blockIdx.x * 256 + threadIdx.x;
        int e4 = t * 4;
        if (e4 < N_EDGES) {
            int4 d4 = *(const int4*)(edst_in + e4);
            int4 s4 = *(const int4*)(esrc_in + e4);
            int sl0 = atomicAdd(&cnt[d4.x], 1);
            int sl1 = atomicAdd(&cnt[d4.y], 1);
            int sl2 = atomicAdd(&cnt[d4.z], 1);
            int sl3 = atomicAdd(&cnt[d4.w], 1);
            if (sl0 < CAP) esrc_pad[(size_t)d4.x * CAP + sl0] = s4.x;
            if (sl1 < CAP) esrc_pad[(size_t)d4.y * CAP + sl1] = s4.y;
            if (sl2 < CAP) esrc_pad[(size_t)d4.z * CAP + sl2] = s4.z;
            if (sl3 < CAP) esrc_pad[(size_t)d4.w * CAP + sl3] = s4.w;
        }
        return;
    }
    int idx = (blockIdx.x - EDGE_BLOCKS) * 256 + threadIdx.x;

    // job A: h0 build (cols 0..43 data, 44..47 zero), row stride 96
    if (idx < N_NODES * 48) {
        int n = idx / 48;
        int c = idx - n * 48;
        float v;
        if (c < 29)       v = x[n * 29 + c];
        else if (c < 32)  v = xdims[n * 3 + (c - 29)];
        else if (c < 44)  v = st_emb[stt[n] * 12 + (c - 32)];
        else              v = 0.f;
        Xc1[(size_t)n * 96 + c] = f2bf(v);
    }
    // job B: Wcat1 row f = [Wr1[f,:44] | 0x4 | Wl1[f,:44] | 0x4]
    if (idx < 128 * 96) {
        int f = idx / 96, k = idx - f * 96;
        float v;
        if (k < 44)       v = Wr1[f * 44 + k];
        else if (k < 48)  v = 0.f;
        else if (k < 92)  v = Wl1[f * 44 + (k - 48)];
        else              v = 0.f;
        Wc1[idx] = f2bf(v);
    }
    // job C: Wcat2 row f = [Wr2[f,:128] | Wl2[f,:128]]
    if (idx < 128 * 256) {
        int f = idx >> 8, k = idx & 255;
        float v = (k < 128) ? Wr2[f * 128 + k] : Wl2[f * 128 + (k - 128)];
        Wc2[idx] = f2bf(v);
    }
    // job D: graph starts from sorted batch
    if (idx < N_NODES) {
        int b = batch[idx];
        int pb = (idx == 0) ? -1 : batch[idx - 1];
        for (int g = pb + 1; g <= b; ++g) starts[g] = idx;
        if (idx == N_NODES - 1)
            for (int g = b + 1; g <= N_GRAPHS; ++g) starts[g] = N_NODES;
    }
}

// ---------------------------------------------------------------------------
// agg1: wave per node. 8-lane groups x 2 clamped loads -> 16 edges/iter.
__global__ __launch_bounds__(256) void agg1_kernel(const int* __restrict__ cnt,
                                                   const int* __restrict__ esrc_pad,
                                                   unsigned short* __restrict__ Xc)
{
    int n = blockIdx.x * 4 + (threadIdx.x >> 6);
    if (n >= N_NODES) return;
    const int lane = threadIdx.x & 63;
    const int grp = lane >> 3;          // 0..7 edge slot
    const int sl  = lane & 7;           // 0..7 col chunk
    const int slc = (sl < 5) ? sl : 5;  // clamp: lanes 6,7 duplicate chunk 5
    int degT = cnt[n];
    int deg  = (degT < CAP) ? degT : CAP;
    int er = esrc_pad[(size_t)n * CAP + lane];   // edges 0..63
    float a0=0.f,a1=0.f,a2=0.f,a3=0.f,a4=0.f,a5=0.f,a6=0.f,a7=0.f;
    const uint4* base = (const uint4*)Xc;
    const int c1 = deg - 1;
    int lim = (deg < 64) ? deg : 64;
    for (int e = 0; e < lim; e += 16) {
        int eA = e + grp, eB = eA + 8;
        int sA = __shfl(er, (eA < c1) ? eA : c1);
        int sB = __shfl(er, (eB < c1) ? eB : c1);
        uint4 va = base[(size_t)sA * 12 + slc];
        uint4 vb = base[(size_t)sB * 12 + slc];
        float mA = (eA < deg) ? 1.f : 0.f;
        float mB = (eB < deg) ? 1.f : 0.f;
        a0 += mA * bflo(va.x) + mB * bflo(vb.x);
        a1 += mA * bfhi(va.x) + mB * bfhi(vb.x);
        a2 += mA * bflo(va.y) + mB * bflo(vb.y);
        a3 += mA * bfhi(va.y) + mB * bfhi(vb.y);
        a4 += mA * bflo(va.z) + mB * bflo(vb.z);
        a5 += mA * bfhi(va.z) + mB * bfhi(vb.z);
        a6 += mA * bflo(va.w) + mB * bflo(vb.w);
        a7 += mA * bfhi(va.w) + mB * bfhi(vb.w);
    }
    for (int e = 64; e < deg; e += 16) {       // deg>64: ~never
        int eA = e + grp, eB = eA + 8;
        int sA = esrc_pad[(size_t)n * CAP + ((eA < c1) ? eA : c1)];
        int sB = esrc_pad[(size_t)n * CAP + ((eB < c1) ? eB : c1)];
        uint4 va = base[(size_t)sA * 12 + slc];
        uint4 vb = base[(size_t)sB * 12 + slc];
        float mA = (eA < deg) ? 1.f : 0.f;
        float mB = (eB < deg) ? 1.f : 0.f;
        a0 += mA * bflo(va.x) + mB * bflo(vb.x);
        a1 += mA * bfhi(va.x) + mB * bfhi(vb.x);
        a2 += mA * bflo(va.y) + mB * bflo(vb.y);
        a3 += mA * bfhi(va.y) + mB * bfhi(vb.y);
        a4 += mA * bflo(va.z) + mB * bflo(vb.z);
        a5 += mA * bfhi(va.z) + mB * bfhi(vb.z);
        a6 += mA * bflo(va.w) + mB * bflo(vb.w);
        a7 += mA * bfhi(va.w) + mB * bfhi(vb.w);
    }
    #pragma unroll
    for (int m = 8; m <= 32; m <<= 1) {
        a0 += __shfl_xor(a0, m); a1 += __shfl_xor(a1, m);
        a2 += __shfl_xor(a2, m); a3 += __shfl_xor(a3, m);
        a4 += __shfl_xor(a4, m); a5 += __shfl_xor(a5, m);
        a6 += __shfl_xor(a6, m); a7 += __shfl_xor(a7, m);
    }
    if (grp == 0 && sl < 6) {
        float inv = (degT > 0) ? 1.f / (float)degT : 0.f;
        uint4 p;
        p.x = (unsigned int)f2bf(a0 * inv) | ((unsigned int)f2bf(a1 * inv) << 16);
        p.y = (unsigned int)f2bf(a2 * inv) | ((unsigned int)f2bf(a3 * inv) << 16);
        p.z = (unsigned int)f2bf(a4 * inv) | ((unsigned int)f2bf(a5 * inv) << 16);
        p.w = (unsigned int)f2bf(a6 * inv) | ((unsigned int)f2bf(a7 * inv) << 16);
        ((uint4*)Xc)[(size_t)n * 12 + 6 + sl] = p;
    }
}

// agg2: wave per node. 16-lane groups x 4 clamped loads -> 16 edges/iter.
__global__ __launch_bounds__(256) void agg2_kernel(const int* __restrict__ cnt,
                                                   const int* __restrict__ esrc_pad,
                                                   unsigned short* __restrict__ Xc)
{
    int n = blockIdx.x * 4 + (threadIdx.x >> 6);
    if (n >= N_NODES) return;
    const int lane = threadIdx.x & 63;
    const int grp = lane >> 4;      // 0..3 edge slot
    const int sl  = lane & 15;      // col chunk
    int degT = cnt[n];
    int deg  = (degT < CAP) ? degT : CAP;
    int er = esrc_pad[(size_t)n * CAP + lane];
    float a0=0.f,a1=0.f,a2=0.f,a3=0.f,a4=0.f,a5=0.f,a6=0.f,a7=0.f;
    const uint4* base = (const uint4*)Xc;
    const int c1 = deg - 1;
    int lim = (deg < 64) ? deg : 64;
    for (int e = 0; e < lim; e += 16) {
        int eA = e + grp, eB = eA + 4, eC = eA + 8, eD = eA + 12;
        int sA = __shfl(er, (eA < c1) ? eA : c1);
        int sB = __shfl(er, (eB < c1) ? eB : c1);
        int sC = __shfl(er, (eC < c1) ? eC : c1);
        int sD = __shfl(er, (eD < c1) ? eD : c1);
        uint4 va = base[(size_t)sA * 32 + sl];
        uint4 vb = base[(size_t)sB * 32 + sl];
        uint4 vc = base[(size_t)sC * 32 + sl];
        uint4 vd = base[(size_t)sD * 32 + sl];
        float mA = (eA < deg) ? 1.f : 0.f;
        float mB = (eB < deg) ? 1.f : 0.f;
        float mC = (eC < deg) ? 1.f : 0.f;
        float mD = (eD < deg) ? 1.f : 0.f;
        a0 += mA * bflo(va.x) + mB * bflo(vb.x) + mC * bflo(vc.x) + mD * bflo(vd.x);
        a1 += mA * bfhi(va.x) + mB * bfhi(vb.x) + mC * bfhi(vc.x) + mD * bfhi(vd.x);
        a2 += mA * bflo(va.y) + mB * bflo(vb.y) + mC * bflo(vc.y) + mD * bflo(vd.y);
        a3 += mA * bfhi(va.y) + mB * bfhi(vb.y) + mC * bfhi(vc.y) + mD * bfhi(vd.y);
        a4 += mA * bflo(va.z) + mB * bflo(vb.z) + mC * bflo(vc.z) + mD * bflo(vd.z);
        a5 += mA * bfhi(va.z) + mB * bfhi(vb.z) + mC * bfhi(vc.z) + mD * bfhi(vd.z);
        a6 += mA * bflo(va.w) + mB * bflo(vb.w) + mC * bflo(vc.w) + mD * bflo(vd.w);
        a7 += mA * bfhi(va.w) + mB * bfhi(vb.w) + mC * bfhi(vc.w) + mD * bfhi(vd.w);
    }
    for (int e = 64; e < deg; e += 16) {       // deg>64: ~never
        int eA = e + grp, eB = eA + 4, eC = eA + 8, eD = eA + 12;
        int sA = esrc_pad[(size_t)n * CAP + ((eA < c1) ? eA : c1)];
        int sB = esrc_pad[(size_t)n * CAP + ((eB < c1) ? eB : c1)];
        int sC = esrc_pad[(size_t)n * CAP + ((eC < c1) ? eC : c1)];
        int sD = esrc_pad[(size_t)n * CAP + ((eD < c1) ? eD : c1)];
        uint4 va = base[(size_t)sA * 32 + sl];
        uint4 vb = base[(size_t)sB * 32 + sl];
        uint4 vc = base[(size_t)sC * 32 + sl];
        uint4 vd = base[(size_t)sD * 32 + sl];
        float mA = (eA < deg) ? 1.f : 0.f;
        float mB = (eB < deg) ? 1.f : 0.f;
        float mC = (eC < deg) ? 1.f : 0.f;
        float mD = (eD < deg) ? 1.f : 0.f;
        a0 += mA * bflo(va.x) + mB * bflo(vb.x) + mC * bflo(vc.x) + mD * bflo(vd.x);
        a1 += mA * bfhi(va.x) + mB * bfhi(vb.x) + mC * bfhi(vc.x) + mD * bfhi(vd.x);
        a2 += mA * bflo(va.y) + mB * bflo(vb.y) + mC * bflo(vc.y) + mD * bflo(vd.y);
        a3 += mA * bfhi(va.y) + mB * bfhi(vb.y) + mC * bfhi(vc.y) + mD * bfhi(vd.y);
        a4 += mA * bflo(va.z) + mB * bflo(vb.z) + mC * bflo(vc.z) + mD * bflo(vd.z);
        a5 += mA * bfhi(va.z) + mB * bfhi(vb.z) + mC * bfhi(vc.z) + mD * bfhi(vd.z);
        a6 += mA * bflo(va.w) + mB * bflo(vb.w) + mC * bflo(vc.w) + mD * bflo(vd.w);
        a7 += mA * bfhi(va.w) + mB * bfhi(vb.w) + mC * bfhi(vc.w) + mD * bfhi(vd.w);
    }
    #pragma unroll
    for (int m = 16; m <= 32; m <<= 1) {
        a0 += __shfl_xor(a0, m); a1 += __shfl_xor(a1, m);
        a2 += __shfl_xor(a2, m); a3 += __shfl_xor(a3, m);
        a4 += __shfl_xor(a4, m); a5 += __shfl_xor(a5, m);
        a6 += __shfl_xor(a6, m); a7 += __shfl_xor(a7, m);
    }
    if (grp == 0) {
        float inv = (degT > 0) ? 1.f / (float)degT : 0.f;
        uint4 p;
        p.x = (unsigned int)f2bf(a0 * inv) | ((unsigned int)f2bf(a1 * inv) << 16);
        p.y = (unsigned int)f2bf(a2 * inv) | ((unsigned int)f2bf(a3 * inv) << 16);
        p.z = (unsigned int)f2bf(a4 * inv) | ((unsigned int)f2bf(a5 * inv) << 16);
        p.w = (unsigned int)f2bf(a6 * inv) | ((unsigned int)f2bf(a7 * inv) << 16);
        ((uint4*)Xc)[(size_t)n * 32 + 16 + sl] = p;
    }
}

// ---------------------------------------------------------------------------
// fused MFMA layer: Out[node][f] = relu(LN(Xcat @ Wcat^T + bl)) as bf16
template <int KPAD>
__global__ __launch_bounds__(256) void mfma_layer_kernel(
    const unsigned short* __restrict__ X, const unsigned short* __restrict__ W,
    const float* __restrict__ bl, const float* __restrict__ g,
    const float* __restrict__ beta,
    unsigned short* __restrict__ Out, int outStride)
{
    const int lane = threadIdx.x & 63;
    const int wv   = threadIdx.x >> 6;
    const int l15  = lane & 15;
    const int l4   = lane >> 4;
    const int row0 = blockIdx.x * 128 + wv * 32;

    int rA0 = row0 + l15;       if (rA0 > N_NODES - 1) rA0 = N_NODES - 1;
    int rA1 = row0 + 16 + l15;  if (rA1 > N_NODES - 1) rA1 = N_NODES - 1;

    f32x4 acc[2][8];
    #pragma unroll
    for (int m = 0; m < 2; ++m)
        #pragma unroll
        for (int n = 0; n < 8; ++n) acc[m][n] = (f32x4){0.f, 0.f, 0.f, 0.f};

    const int kb = l4 * 8;
    #pragma unroll
    for (int ks = 0; ks < KPAD / 32; ++ks) {
        const int k = ks * 32 + kb;
        bf16x8 a0 = *(const bf16x8*)(X + (size_t)rA0 * KPAD + k);
        bf16x8 a1 = *(const bf16x8*)(X + (size_t)rA1 * KPAD + k);
        #pragma unroll
        for (int ni = 0; ni < 8; ++ni) {
            bf16x8 b = *(const bf16x8*)(W + (size_t)(ni * 16 + l15) * KPAD + k);
            acc[0][ni] = __builtin_amdgcn_mfma_f32_16x16x32_bf16(a0, b, acc[0][ni], 0, 0, 0);
            acc[1][ni] = __builtin_amdgcn_mfma_f32_16x16x32_bf16(a1, b, acc[1][ni], 0, 0, 0);
        }
    }

    float blv[8], gv[8], bev[8];
    #pragma unroll
    for (int ni = 0; ni < 8; ++ni) {
        int f = ni * 16 + l15;
        blv[ni] = bl[f]; gv[ni] = g[f]; bev[ni] = beta[f];
    }

    #pragma unroll
    for (int mi = 0; mi < 2; ++mi) {
        #pragma unroll
        for (int r = 0; r < 4; ++r) {
            float v[8];
            float s1 = 0.f, s2 = 0.f;
            #pragma unroll
            for (int ni = 0; ni < 8; ++ni) {
                float t = acc[mi][ni][r] + blv[ni];
                v[ni] = t; s1 += t; s2 += t * t;
            }
            #pragma unroll
            for (int m = 8; m >= 1; m >>= 1) {
                s1 += __shfl_xor(s1, m);
                s2 += __shfl_xor(s2, m);
            }
            float mu   = s1 * (1.f / 128.f);
            float var  = s2 * (1.f / 128.f) - mu * mu;
            float rstd = rsqrtf(var + LN_EPS);
            int node = row0 + mi * 16 + l4 * 4 + r;
            if (node < N_NODES) {
                #pragma unroll
                for (int ni = 0; ni < 8; ++ni) {
                    float o = gv[ni] * (v[ni] - mu) * rstd + bev[ni];
                    o = fmaxf(o, 0.f);
                    Out[(size_t)node * outStride + ni * 16 + l15] = f2bf(o);
                }
            }
        }
    }
}

// ---------------------------------------------------------------------------
// fused pooling (mean+max) + linear head. 1 block / graph, 256 threads.
__global__ __launch_bounds__(256) void poolhead_kernel(const unsigned short* __restrict__ h2,
                                                       const int* __restrict__ starts,
                                                       const float* __restrict__ Wlin,
                                                       const float* __restrict__ blin,
                                                       float* __restrict__ out)
{
    const int g  = blockIdx.x;
    const int j2 = threadIdx.x & 63;   // col pair 2*j2, 2*j2+1
    const int h  = threadIdx.x >> 6;   // row group 0..3
    const int s0 = starts[g], s1 = starts[g + 1];
    float sa = 0.f, sb = 0.f, ma = -INFINITY, mb = -INFINITY;
    const unsigned int* base = (const unsigned int*)h2;   // row stride 64 uints
    int n = s0 + h;
    for (; n + 4 < s1; n += 8) {
        unsigned int u0 = base[(size_t)n * 64 + j2];
        unsigned int u1 = base[(size_t)(n + 4) * 64 + j2];
        float l0 = bflo(u0), h0 = bfhi(u0);
        float l1 = bflo(u1), h1 = bfhi(u1);
        sa += l0 + l1; sb += h0 + h1;
        ma = fmaxf(ma, fmaxf(l0, l1));
        mb = fmaxf(mb, fmaxf(h0, h1));
    }
    if (n < s1) {
        unsigned int u = base[(size_t)n * 64 + j2];
        float lo = bflo(u), hi = bfhi(u);
        sa += lo; sb += hi;
        ma = fmaxf(ma, lo); mb = fmaxf(mb, hi);
    }
    __shared__ float red[4][4][64];
    __shared__ float pooled[256];
    red[h][0][j2] = sa; red[h][1][j2] = sb; red[h][2][j2] = ma; red[h][3][j2] = mb;
    __syncthreads();
    if (h == 0) {
        #pragma unroll
        for (int o = 1; o < 4; ++o) {
            sa += red[o][0][j2]; sb += red[o][1][j2];
            ma = fmaxf(ma, red[o][2][j2]); mb = fmaxf(mb, red[o][3][j2]);
        }
        int c = s1 - s0;
        float inv = (c > 0) ? 1.f / (float)c : 0.f;
        pooled[2 * j2]           = sa * inv;
        pooled[2 * j2 + 1]       = sb * inv;
        pooled[128 + 2 * j2]     = (c > 0) ? ma : 0.f;
        pooled[128 + 2 * j2 + 1] = (c > 0) ? mb : 0.f;
    }
    __syncthreads();
    if (threadIdx.x < 10) {
        const float* w = Wlin + threadIdx.x * 256;
        float acc = blin[threadIdx.x];
        for (int k = 0; k < 256; ++k) acc += pooled[k] * w[k];
        out[g * 10 + threadIdx.x] = acc;
    }
}

// ---------------------------------------------------------------------------
extern "C" void kernel_launch(void* const* d_in, const int* in_sizes, int n_in,
                              void* d_out, int out_size, void* d_ws, size_t ws_size,
                              hipStream_t stream)
{
    const float* x      = (const float*)d_in[0];
    const float* xdims  = (const float*)d_in[1];
    const int*   stt    = (const int*)d_in[2];
    const int*   eidx   = (const int*)d_in[3];
    const int*   batch  = (const int*)d_in[4];
    const float* st_emb = (const float*)d_in[5];
    const float* Wl1 = (const float*)d_in[6];
    const float* bl1 = (const float*)d_in[7];
    const float* Wr1 = (const float*)d_in[8];
    const float* g1  = (const float*)d_in[9];
    const float* be1 = (const float*)d_in[10];
    const float* Wl2 = (const float*)d_in[11];
    const float* bl2 = (const float*)d_in[12];
    const float* Wr2 = (const float*)d_in[13];
    const float* g2  = (const float*)d_in[14];
    const float* be2 = (const float*)d_in[15];
    const float* Wlin = (const float*)d_in[16];
    const float* blin = (const float*)d_in[17];
    float* out = (float*)d_out;

    const int* esrc_in = eidx;
    const int* edst_in = eidx + N_EDGES;

    char* ws = (char*)d_ws;
    size_t o = 0;
    auto carve = [&](size_t bytes) { void* p = ws + o; o = (o + bytes + 255) & ~(size_t)255; return p; };
    unsigned short* Xc1  = (unsigned short*)carve((size_t)N_NODES * 96 * 2);
    unsigned short* Xc2  = (unsigned short*)carve((size_t)N_NODES * 256 * 2);
    unsigned short* h2bf = (unsigned short*)carve((size_t)N_NODES * 128 * 2);
    unsigned short* Wc1  = (unsigned short*)carve((size_t)128 * 96 * 2);
    unsigned short* Wc2  = (unsigned short*)carve((size_t)128 * 256 * 2);
    int*   cnt      = (int*)carve((size_t)N_NODES * 4);
    int*   esrc_pad = (int*)carve((size_t)N_NODES * CAP * 4);
    int*   starts   = (int*)carve((size_t)(N_GRAPHS + 1) * 4);
    (void)ws_size;

    // 1. zero degree counters (tiny)
    zero_kernel<<<(N_NODES + 255) / 256, 256, 0, stream>>>(cnt);

    // 2. fused edge fill (ILP-4) + h0 + weight concat + graph starts
    prep_fill_kernel<<<EDGE_BLOCKS + PREP_BLOCKS, 256, 0, stream>>>(
        x, xdims, stt, st_emb, Wl1, Wr1, Wl2, Wr2, batch,
        esrc_in, edst_in, Xc1, Wc1, Wc2, cnt, esrc_pad, starts);

    // 3-4. layer 1
    agg1_kernel<<<(N_NODES + 3) / 4, 256, 0, stream>>>(cnt, esrc_pad, Xc1);
    mfma_layer_kernel<96><<<(N_NODES + 127) / 128, 256, 0, stream>>>(
        Xc1, Wc1, bl1, g1, be1, Xc2, 256);

    // 5-6. layer 2
    agg2_kernel<<<(N_NODES + 3) / 4, 256, 0, stream>>>(cnt, esrc_pad, Xc2);
    mfma_layer_kernel<256><<<(N_NODES + 127) / 128, 256, 0, stream>>>(
        Xc2, Wc2, bl2, g2, be2, h2bf, 128);

    // 7. fused pooling + head
    poolhead_kernel<<<N_GRAPHS, 256, 0, stream>>>(h2bf, starts, Wlin, blin, out);
}